// Round 8
// baseline (318.079 us; speedup 1.0000x reference)
//
#include <hip/hip_runtime.h>
#include <stdint.h>

typedef unsigned short u16;
typedef uint32_t u32;
typedef __attribute__((ext_vector_type(8))) short short8;
typedef __attribute__((ext_vector_type(4))) float f32x4;
typedef __attribute__((ext_vector_type(4))) u32 u32x4;
typedef __attribute__((ext_vector_type(2))) u32 u32x2;
typedef __attribute__((ext_vector_type(4))) unsigned short u16x4;

#define BS_ 4096   // B*S rows
#define S_ 2048
#define HID_ 2048
#define KVB 32

__device__ __forceinline__ float bf2f(u16 u) { union { u32 i; float f; } v; v.i = ((u32)u) << 16; return v.f; }
__device__ __forceinline__ u16 f2bf(float f) {
  union { float f; u32 i; } v; v.f = f;
  u32 r = v.i + 0x7fffu + ((v.i >> 16) & 1u);
  return (u16)(r >> 16);
}

__device__ __forceinline__ void gload16(const void* gsrc, void* ldst) {
  __builtin_amdgcn_global_load_lds(
      (const __attribute__((address_space(1))) void*)gsrc,
      (__attribute__((address_space(3))) void*)ldst, 16, 0, 0);
}

// ---------------- elementwise convert fp32 -> bf16 ----------------
__global__ __launch_bounds__(256) void conv_f2b(const float* __restrict__ in, u16* __restrict__ out, int n4) {
  int i = blockIdx.x * 256 + threadIdx.x;
  if (i < n4) {
    float4 v = ((const float4*)in)[i];
    u16x4 o;
    o.x = f2bf(v.x); o.y = f2bf(v.y); o.z = f2bf(v.z); o.w = f2bf(v.w);
    ((u16x4*)out)[i] = o;
  }
}

// ---------------- transpose + convert: W[K][N] fp32 -> WT[N][K] bf16 ----------------
__global__ __launch_bounds__(256) void transpose_conv(const float* __restrict__ W, u16* __restrict__ WT,
                                                      int K, int N) {
  __shared__ float tile[64][65];
  const int t = threadIdx.x;
  const int kb = blockIdx.y * 64, nb = blockIdx.x * 64;
#pragma unroll
  for (int c = 0; c < 4; ++c) {
    int idx = c * 256 + t;
    int row = idx >> 4;
    int col4 = (idx & 15) * 4;
    float4 v = *(const float4*)&W[(size_t)(kb + row) * N + nb + col4];
    tile[row][col4 + 0] = v.x; tile[row][col4 + 1] = v.y;
    tile[row][col4 + 2] = v.z; tile[row][col4 + 3] = v.w;
  }
  __syncthreads();
#pragma unroll
  for (int c = 0; c < 4; ++c) {
    int idx = c * 256 + t;
    int n = idx >> 4;
    int k4 = (idx & 15) * 4;
    u16x4 o;
    o.x = f2bf(tile[k4 + 0][n]); o.y = f2bf(tile[k4 + 1][n]);
    o.z = f2bf(tile[k4 + 2][n]); o.w = f2bf(tile[k4 + 3][n]);
    *(u16x4*)&WT[(size_t)(nb + n) * K + kb + k4] = o;
  }
}

// ---------------- bias concat ----------------
__global__ __launch_bounds__(256) void concat_bias(const float* __restrict__ b_dkv, const float* __restrict__ b_dq,
                                                   const float* __restrict__ b_uk, const float* __restrict__ b_uv,
                                                   float* __restrict__ bc1, float* __restrict__ bc2) {
  int i = blockIdx.x * 256 + threadIdx.x;
  if (i < 512) bc1[i] = b_dkv[i];
  else if (i < 2048) bc1[i] = b_dq[i - 512];
  else if (i < 4096) bc2[i - 2048] = b_uk[i - 2048];
  else if (i < 6144) bc2[i - 2048] = b_uv[i - 4096];
}

// ---------------- V transpose: kvbuf[b][s][2048 + h*128 + d] -> VT[(b*16+h)][d][s] ----------------
__global__ __launch_bounds__(256) void vtrans(const u16* __restrict__ KVin, u16* __restrict__ VT) {
  __shared__ u16 tile[64][136];
  const int t = threadIdx.x;
  const int st0 = blockIdx.x * 64;
  const int bh = blockIdx.y;
  const int bb = bh >> 4, h = bh & 15;
  const u16* src = KVin + (size_t)bb * S_ * 4096 + 2048 + (size_t)h * 128;
  u16* dst = VT + (size_t)bh * 128 * S_;
#pragma unroll
  for (int c = 0; c < 4; ++c) {
    int idx = c * 256 + t;
    int s = idx >> 4, ch = idx & 15;
    short8 v = *(const short8*)&src[(size_t)(st0 + s) * 4096 + ch * 8];
    *(short8*)&tile[s][ch * 8] = v;
  }
  __syncthreads();
#pragma unroll
  for (int c = 0; c < 4; ++c) {
    int idx = c * 256 + t;
    int d = idx >> 3, ch = idx & 7;
    short8 o;
#pragma unroll
    for (int j = 0; j < 8; ++j) o[j] = tile[ch * 8 + j][d];
    *(short8*)&dst[(size_t)d * S_ + st0 + ch * 8] = o;
  }
}

// ---------------- RoPE table, interleaved (cos,sin) pairs: cs[(pos*64+i)*2 .. +1] ----------------
__global__ __launch_bounds__(256) void rope_table(float* __restrict__ cs) {
  int idx = blockIdx.x * 256 + threadIdx.x;   // 2048*64
  int pos = idx >> 6, i = idx & 63;
  float inv = powf(10000.f, -(float)i / 64.f);
  float a = (float)pos * inv;
  cs[idx * 2] = cosf(a);
  cs[idx * 2 + 1] = sinf(a);
}

// ---------------- GEMM: swapped-operand epilogue + optional fused RoPE ----------------
// C[M][N] = A[M rows, lda][0..K) * BT[N][K]^T + bias ; cols < ROPE get interleaved-pair rotation.
template <int OUTF32, int ROPE>
__global__ __launch_bounds__(256) void gemm_bt(const u16* __restrict__ A, int lda,
                                               const u16* __restrict__ BT,
                                               const float* __restrict__ bias,
                                               const float* __restrict__ cs,
                                               void* __restrict__ Cout,
                                               int M, int N, int K) {
  __shared__ u16 As[128 * 64];
  __shared__ u16 Bs[128 * 64];
  const int t = threadIdx.x;
  const int lane = t & 63, wave = t >> 6;
  const int wm = wave >> 1, wn = wave & 1;
  const int gx = gridDim.x;
  const int nwg = gx * gridDim.y;
  const int flat = blockIdx.y * gx + blockIdx.x;
  const int swz = (flat & 7) * (nwg >> 3) + (flat >> 3);
  const int tn = swz % gx, tm = swz / gx;
  const int r16 = lane & 15, q4 = lane >> 4;

  f32x4 acc[4][4];
#pragma unroll
  for (int m = 0; m < 4; ++m)
#pragma unroll
    for (int n = 0; n < 4; ++n) acc[m][n] = (f32x4){0.f, 0.f, 0.f, 0.f};

  for (int kt = 0; kt < K; kt += 64) {
#pragma unroll
    for (int c = 0; c < 4; ++c) {
      int idx = c * 256 + t;
      int row = idx >> 3, ch = idx & 7;
      gload16(&A[(size_t)(tm * 128 + row) * lda + kt + ch * 8], (char*)As + idx * 16);
      gload16(&BT[(size_t)(tn * 128 + row) * K + kt + ch * 8], (char*)Bs + idx * 16);
    }
    __syncthreads();
#pragma unroll
    for (int kk = 0; kk < 64; kk += 32) {
      short8 af[4], bfv[4];
#pragma unroll
      for (int m = 0; m < 4; ++m)
        af[m] = *(const short8*)&As[(wm * 64 + m * 16 + r16) * 64 + kk + q4 * 8];
#pragma unroll
      for (int n = 0; n < 4; ++n)
        bfv[n] = *(const short8*)&Bs[(wn * 64 + n * 16 + r16) * 64 + kk + q4 * 8];
      __builtin_amdgcn_s_setprio(1);
#pragma unroll
      for (int m = 0; m < 4; ++m)
#pragma unroll
        for (int n = 0; n < 4; ++n)
          acc[m][n] = __builtin_amdgcn_mfma_f32_16x16x32_bf16(bfv[n], af[m], acc[m][n], 0, 0, 0);
      __builtin_amdgcn_s_setprio(0);
    }
    __syncthreads();
  }
#pragma unroll
  for (int n = 0; n < 4; ++n) {
    int gc0 = tn * 128 + wn * 64 + n * 16 + q4 * 4;
    float4 bv4 = *(const float4*)&bias[gc0];
    const int i0 = (gc0 & 127) >> 1;
#pragma unroll
    for (int m = 0; m < 4; ++m) {
      int grow = tm * 128 + wm * 64 + m * 16 + r16;
      float v0 = acc[m][n][0] + bv4.x, v1 = acc[m][n][1] + bv4.y;
      float v2 = acc[m][n][2] + bv4.z, v3 = acc[m][n][3] + bv4.w;
      if (ROPE && gc0 < ROPE) {
        int s = grow & 2047;
        float4 cp = *(const float4*)&cs[((size_t)s * 64 + i0) * 2];   // c0,s0,c1,s1
        float y0 = v0 * cp.x - v1 * cp.y;
        float y1 = v0 * cp.y + v1 * cp.x;
        float y2 = v2 * cp.z - v3 * cp.w;
        float y3 = v2 * cp.w + v3 * cp.z;
        v0 = y0; v1 = y1; v2 = y2; v3 = y3;
      }
      if (OUTF32) {
        float4 o; o.x = v0; o.y = v1; o.z = v2; o.w = v3;
        *(float4*)&((float*)Cout)[(size_t)grow * N + gc0] = o;
      } else {
        u16x4 o; o.x = f2bf(v0); o.y = f2bf(v1); o.z = f2bf(v2); o.w = f2bf(v3);
        *(u16x4*)&((u16*)Cout)[(size_t)grow * N + gc0] = o;
      }
    }
  }
}

// ---------------- causal flash attention v7: KVB=32, 4 blocks/CU ----------------
// 512 blocks: xcd=b&7, u=b>>3, p=u&15, g4=u>>4; bh=g4*8+xcd. Segments qt=p then qt=31-p
// (64-row q-tiles): exactly 68 KV-tiles per block. 4 waves x 16 q-rows, swapped QK^T.
__global__ __launch_bounds__(256, 4) void attn_kernel(const u16* __restrict__ Q, const u16* __restrict__ K,
                                                      int kld, const u16* __restrict__ VT,
                                                      u16* __restrict__ O) {
  __shared__ u16 Kl[2][KVB * 128];   // 8KB each, [kv][d] rows 256B, chunk^(row&7) swizzle
  __shared__ u16 Vl[2][128 * KVB];   // 8KB each, [d][kv] rows 64B, chunk^((row>>1)&3) swizzle
  __shared__ u16 Pl[4][16 * KVB];    // per-wave P [q][kv], 1KB, chunk^((row>>1)&3) swizzle
  const int t = threadIdx.x;
  const int lane = t & 63, w = t >> 6;
  const int r16 = lane & 15, q4 = lane >> 4;
  const int b = blockIdx.x;
  const int xcd = b & 7, u = b >> 3;
  const int p = u & 15, g4 = u >> 4;
  const int bh = g4 * 8 + xcd;
  const int bb = bh >> 4, h = bh & 15;
  const u16* Qb = Q + (size_t)bb * S_ * HID_ + (size_t)h * 128;
  const u16* Kb = K + (size_t)bb * S_ * kld + (size_t)h * 128;
  const u16* VTb = VT + (size_t)bh * 128 * S_;
  u16* Ob = O + (size_t)bb * S_ * HID_ + (size_t)h * 128;

  auto stage = [&](int buf, int kvbase) {
#pragma unroll
    for (int c = 0; c < 2; ++c) {
      int s = c * 256 + t;
      int row = s >> 4;
      int chs = (s & 15) ^ (row & 7);
      gload16(&Kb[(size_t)(kvbase + row) * kld + chs * 8], (char*)Kl[buf] + s * 16);
    }
#pragma unroll
    for (int c = 0; c < 2; ++c) {
      int s = c * 256 + t;
      int row = s >> 2;
      int chs = (s & 3) ^ ((row >> 1) & 3);
      gload16(&VTb[(size_t)row * S_ + kvbase + chs * 8], (char*)Vl[buf] + s * 16);
    }
  };

  u16* Pw = &Pl[w][0];
  const float SCALE = 0.08838834764831845f;
  const int pswz = (r16 >> 1) & 3;

#pragma unroll
  for (int seg = 0; seg < 2; ++seg) {
    const int qt = seg ? (31 - p) : p;
    const int nt = 2 * qt + 2;
    const int qrow0 = qt * 64 + w * 16;
    const int q = qrow0 + r16;

    short8 qf[4];
#pragma unroll
    for (int dk = 0; dk < 4; ++dk)
      qf[dk] = *(const short8*)&Qb[(size_t)q * HID_ + dk * 32 + q4 * 8];

    f32x4 ao[8];
#pragma unroll
    for (int dn = 0; dn < 8; ++dn) ao[dn] = (f32x4){0.f, 0.f, 0.f, 0.f};
    float mr = -1e30f, lr = 0.f;

    stage(0, 0);
    __syncthreads();

    for (int ti = 0; ti < nt; ++ti) {
      const int buf = ti & 1;
      const int kv0 = ti * KVB;
      if (ti + 1 < nt) stage(buf ^ 1, kv0 + KVB);

      // ---- QK^T swapped: lane owns q-col, kv in regs ----
      f32x4 sc[2];
      sc[0] = (f32x4){0.f, 0.f, 0.f, 0.f};
      sc[1] = (f32x4){0.f, 0.f, 0.f, 0.f};
#pragma unroll
      for (int dk = 0; dk < 4; ++dk) {
        short8 kf[2];
#pragma unroll
        for (int n = 0; n < 2; ++n) {
          int kr = n * 16 + r16;
          int ba = (kr * 256 + dk * 64 + q4 * 16) ^ ((kr & 7) << 4);
          kf[n] = *(const short8*)((const char*)Kl[buf] + ba);
        }
        __builtin_amdgcn_s_setprio(1);
        sc[0] = __builtin_amdgcn_mfma_f32_16x16x32_bf16(kf[0], qf[dk], sc[0], 0, 0, 0);
        sc[1] = __builtin_amdgcn_mfma_f32_16x16x32_bf16(kf[1], qf[dk], sc[1], 0, 0, 0);
        __builtin_amdgcn_s_setprio(0);
      }
      // ---- scale + causal mask ----
      const bool nm = (kv0 + 31 > qrow0);
#pragma unroll
      for (int n = 0; n < 2; ++n)
#pragma unroll
        for (int j = 0; j < 4; ++j) {
          float sv = sc[n][j] * SCALE;
          if (nm) {
            int kv = kv0 + n * 16 + q4 * 4 + j;
            if (kv > q) sv = -1e30f;
          }
          sc[n][j] = sv;
        }
      // ---- online softmax ----
      float tm = sc[0][0];
#pragma unroll
      for (int n = 0; n < 2; ++n)
#pragma unroll
        for (int j = 0; j < 4; ++j) tm = fmaxf(tm, sc[n][j]);
      tm = fmaxf(tm, __shfl_xor(tm, 16));
      tm = fmaxf(tm, __shfl_xor(tm, 32));
      if (!__all(tm - mr <= 8.0f)) {
        float mnew = fmaxf(mr, tm);
        float fsc = __expf(mr - mnew);
        lr *= fsc; mr = mnew;
#pragma unroll
        for (int dn = 0; dn < 8; ++dn) ao[dn] *= fsc;
      }
      float ps = 0.f;
#pragma unroll
      for (int n = 0; n < 2; ++n)
#pragma unroll
        for (int j = 0; j < 4; ++j) {
          float pv = __expf(sc[n][j] - mr);
          sc[n][j] = pv;
          ps += pv;
        }
      ps += __shfl_xor(ps, 16);
      ps += __shfl_xor(ps, 32);
      lr += ps;
      // ---- P -> LDS: cvt_pk, two b64 writes ----
#pragma unroll
      for (int n = 0; n < 2; ++n) {
        u32 lo, hi;
        asm("v_cvt_pk_bf16_f32 %0, %1, %2" : "=v"(lo) : "v"(sc[n][0]), "v"(sc[n][1]));
        asm("v_cvt_pk_bf16_f32 %0, %1, %2" : "=v"(hi) : "v"(sc[n][2]), "v"(sc[n][3]));
        u32x2 pr; pr.x = lo; pr.y = hi;
        int chunk = (n * 2 + (q4 >> 1)) ^ pswz;
        int ba = r16 * 64 + chunk * 16 + (q4 & 1) * 8;
        *(u32x2*)((char*)Pw + ba) = pr;
      }
      // ---- PV: O^T = mfma(A=V^T-frag, B=P^T-frag) ----
      {
        int bp = r16 * 64 + ((q4 ^ pswz) * 16);
        short8 pb = *(const short8*)((const char*)Pw + bp);
        __builtin_amdgcn_s_setprio(1);
#pragma unroll
        for (int dn = 0; dn < 8; ++dn) {
          int dr = dn * 16 + r16;
          int bv = dr * 64 + ((q4 ^ ((dr >> 1) & 3)) * 16);
          short8 vf = *(const short8*)((const char*)Vl[buf] + bv);
          ao[dn] = __builtin_amdgcn_mfma_f32_16x16x32_bf16(vf, pb, ao[dn], 0, 0, 0);
        }
        __builtin_amdgcn_s_setprio(0);
      }
      __syncthreads();   // next tile's DMA landed; buffers safe to swap
    }

    // ---- epilogue: O[q][d] ----
    float inv = 1.f / lr;
#pragma unroll
    for (int dn = 0; dn < 8; ++dn) {
      u16x4 o;
#pragma unroll
      for (int j = 0; j < 4; ++j) o[j] = f2bf(ao[dn][j] * inv);
      *(u16x4*)&Ob[(size_t)q * HID_ + dn * 16 + q4 * 4] = o;
    }
    __syncthreads();   // segment boundary before restaging buf 0
  }
}

// ---------------- host launch ----------------
extern "C" void kernel_launch(void* const* d_in, const int* in_sizes, int n_in,
                              void* d_out, int out_size, void* d_ws, size_t ws_size,
                              hipStream_t stream) {
  (void)in_sizes; (void)n_in; (void)out_size; (void)ws_size;
  const float* x     = (const float*)d_in[0];
  const float* W_dkv = (const float*)d_in[2];
  const float* b_dkv = (const float*)d_in[3];
  const float* W_uk  = (const float*)d_in[4];
  const float* b_uk  = (const float*)d_in[5];
  const float* W_uv  = (const float*)d_in[6];
  const float* b_uv  = (const float*)d_in[7];
  const float* W_dq  = (const float*)d_in[8];
  const float* b_dq  = (const float*)d_in[9];
  const float* W_uq  = (const float*)d_in[10];
  const float* b_uq  = (const float*)d_in[11];
  const float* W_o   = (const float*)d_in[12];
  const float* b_o   = (const float*)d_in[13];
  float* out = (float*)d_out;

  char* ws = (char*)d_ws;
  size_t off = 0;
  auto carve = [&](size_t bytes) { void* p = ws + off; off += (bytes + 255) & ~(size_t)255; return p; };
  u16* xb     = (u16*)carve((size_t)BS_ * 2048 * 2);      // reused as VT after GEMM1
  u16* WdkvqT = (u16*)carve((size_t)2048 * 2048 * 2);     // rows 0-511 dkv, 512-2047 dq
  u16* WukvT  = (u16*)carve((size_t)4096 * 512 * 2);      // rows 0-2047 uk, 2048-4095 uv
  u16* WuqT   = (u16*)carve((size_t)2048 * 1536 * 2);
  u16* WoT    = (u16*)carve((size_t)2048 * 2048 * 2);
  u16* kvq1   = (u16*)carve((size_t)BS_ * 2048 * 2);      // cols 0-511 kv, 512-2047 q1
  u16* kvbuf  = (u16*)carve((size_t)BS_ * 4096 * 2);      // cols 0-2047 k(roped), 2048-4095 v
  u16* qb     = (u16*)carve((size_t)BS_ * 2048 * 2);
  u16* aob    = (u16*)carve((size_t)BS_ * 2048 * 2);
  float* cs   = (float*)carve((size_t)2048 * 64 * 2 * 4); // interleaved cos/sin
  float* bc1  = (float*)carve((size_t)2048 * 4);
  float* bc2  = (float*)carve((size_t)4096 * 4);
  u16* VT     = xb;   // xb dead after GEMM1

  conv_f2b<<<dim3(BS_ * 2048 / 4 / 256), 256, 0, stream>>>(x, xb, BS_ * 2048 / 4);
  transpose_conv<<<dim3(512 / 64, 2048 / 64), 256, 0, stream>>>(W_dkv, WdkvqT, 2048, 512);
  transpose_conv<<<dim3(1536 / 64, 2048 / 64), 256, 0, stream>>>(W_dq, WdkvqT + (size_t)512 * 2048, 2048, 1536);
  transpose_conv<<<dim3(2048 / 64, 512 / 64), 256, 0, stream>>>(W_uk, WukvT, 512, 2048);
  transpose_conv<<<dim3(2048 / 64, 512 / 64), 256, 0, stream>>>(W_uv, WukvT + (size_t)2048 * 512, 512, 2048);
  transpose_conv<<<dim3(2048 / 64, 1536 / 64), 256, 0, stream>>>(W_uq, WuqT, 1536, 2048);
  transpose_conv<<<dim3(2048 / 64, 2048 / 64), 256, 0, stream>>>(W_o, WoT, 2048, 2048);
  rope_table<<<dim3(512), 256, 0, stream>>>(cs);
  concat_bias<<<dim3(24), 256, 0, stream>>>(b_dkv, b_dq, b_uk, b_uv, bc1, bc2);

  // GEMM1: x @ {W_dkv|W_dq} -> kvq1
  gemm_bt<0, 0><<<dim3(2048 / 128, BS_ / 128), 256, 0, stream>>>(xb, 2048, WdkvqT, bc1, nullptr, kvq1, BS_, 2048, 2048);
  // GEMM2: kv @ {W_uk|W_uv} -> kvbuf, rope on k-cols (<2048)
  gemm_bt<0, 2048><<<dim3(4096 / 128, BS_ / 128), 256, 0, stream>>>(kvq1, 2048, WukvT, bc2, cs, kvbuf, BS_, 4096, 512);
  // GEMM3: q1 @ W_uq -> qb, rope on all cols
  gemm_bt<0, 2048><<<dim3(2048 / 128, BS_ / 128), 256, 0, stream>>>(kvq1 + 512, 2048, WuqT, b_uq, cs, qb, BS_, 2048, 1536);

  vtrans<<<dim3(S_ / 64, 32), 256, 0, stream>>>(kvbuf, VT);

  attn_kernel<<<dim3(512), 256, 0, stream>>>(qb, kvbuf, 4096, VT, aob);

  // GEMM4: attn_out @ W_o -> out (fp32)
  gemm_bt<1, 0><<<dim3(2048 / 128, BS_ / 128), 256, 0, stream>>>(aob, 2048, WoT, b_o, nullptr, out, BS_, 2048, 2048);
}

// Round 9
// 317.422 us; speedup vs baseline: 1.0021x; 1.0021x over previous
//
#include <hip/hip_runtime.h>
#include <stdint.h>

typedef unsigned short u16;
typedef uint32_t u32;
typedef __attribute__((ext_vector_type(8))) short short8;
typedef __attribute__((ext_vector_type(4))) float f32x4;
typedef __attribute__((ext_vector_type(4))) u32 u32x4;
typedef __attribute__((ext_vector_type(2))) u32 u32x2;
typedef __attribute__((ext_vector_type(4))) unsigned short u16x4;

#define BS_ 4096   // B*S rows
#define S_ 2048
#define HID_ 2048
#define KVB 64

__device__ __forceinline__ float bf2f(u16 u) { union { u32 i; float f; } v; v.i = ((u32)u) << 16; return v.f; }
__device__ __forceinline__ u16 f2bf(float f) {
  union { float f; u32 i; } v; v.f = f;
  u32 r = v.i + 0x7fffu + ((v.i >> 16) & 1u);
  return (u16)(r >> 16);
}

__device__ __forceinline__ void gload16(const void* gsrc, void* ldst) {
  __builtin_amdgcn_global_load_lds(
      (const __attribute__((address_space(1))) void*)gsrc,
      (__attribute__((address_space(3))) void*)ldst, 16, 0, 0);
}

// ---------------- elementwise convert fp32 -> bf16 ----------------
__global__ __launch_bounds__(256) void conv_f2b(const float* __restrict__ in, u16* __restrict__ out, int n4) {
  int i = blockIdx.x * 256 + threadIdx.x;
  if (i < n4) {
    float4 v = ((const float4*)in)[i];
    u16x4 o;
    o.x = f2bf(v.x); o.y = f2bf(v.y); o.z = f2bf(v.z); o.w = f2bf(v.w);
    ((u16x4*)out)[i] = o;
  }
}

// ---------------- transpose + convert: W[K][N] fp32 -> WT[N][K] bf16 ----------------
__global__ __launch_bounds__(256) void transpose_conv(const float* __restrict__ W, u16* __restrict__ WT,
                                                      int K, int N) {
  __shared__ float tile[64][65];
  const int t = threadIdx.x;
  const int kb = blockIdx.y * 64, nb = blockIdx.x * 64;
#pragma unroll
  for (int c = 0; c < 4; ++c) {
    int idx = c * 256 + t;
    int row = idx >> 4;
    int col4 = (idx & 15) * 4;
    float4 v = *(const float4*)&W[(size_t)(kb + row) * N + nb + col4];
    tile[row][col4 + 0] = v.x; tile[row][col4 + 1] = v.y;
    tile[row][col4 + 2] = v.z; tile[row][col4 + 3] = v.w;
  }
  __syncthreads();
#pragma unroll
  for (int c = 0; c < 4; ++c) {
    int idx = c * 256 + t;
    int n = idx >> 4;
    int k4 = (idx & 15) * 4;
    u16x4 o;
    o.x = f2bf(tile[k4 + 0][n]); o.y = f2bf(tile[k4 + 1][n]);
    o.z = f2bf(tile[k4 + 2][n]); o.w = f2bf(tile[k4 + 3][n]);
    *(u16x4*)&WT[(size_t)(nb + n) * K + kb + k4] = o;
  }
}

// ---------------- bias concat ----------------
__global__ __launch_bounds__(256) void concat_bias(const float* __restrict__ b_dkv, const float* __restrict__ b_dq,
                                                   const float* __restrict__ b_uk, const float* __restrict__ b_uv,
                                                   float* __restrict__ bc1, float* __restrict__ bc2) {
  int i = blockIdx.x * 256 + threadIdx.x;
  if (i < 512) bc1[i] = b_dkv[i];
  else if (i < 2048) bc1[i] = b_dq[i - 512];
  else if (i < 4096) bc2[i - 2048] = b_uk[i - 2048];
  else if (i < 6144) bc2[i - 2048] = b_uv[i - 4096];
}

// ---------------- V transpose: kvbuf[b][s][2048 + h*128 + d] -> VT[(b*16+h)][d][s] ----------------
__global__ __launch_bounds__(256) void vtrans(const u16* __restrict__ KVin, u16* __restrict__ VT) {
  __shared__ u16 tile[64][136];
  const int t = threadIdx.x;
  const int st0 = blockIdx.x * 64;
  const int bh = blockIdx.y;
  const int bb = bh >> 4, h = bh & 15;
  const u16* src = KVin + (size_t)bb * S_ * 4096 + 2048 + (size_t)h * 128;
  u16* dst = VT + (size_t)bh * 128 * S_;
#pragma unroll
  for (int c = 0; c < 4; ++c) {
    int idx = c * 256 + t;
    int s = idx >> 4, ch = idx & 15;
    short8 v = *(const short8*)&src[(size_t)(st0 + s) * 4096 + ch * 8];
    *(short8*)&tile[s][ch * 8] = v;
  }
  __syncthreads();
#pragma unroll
  for (int c = 0; c < 4; ++c) {
    int idx = c * 256 + t;
    int d = idx >> 3, ch = idx & 7;
    short8 o;
#pragma unroll
    for (int j = 0; j < 8; ++j) o[j] = tile[ch * 8 + j][d];
    *(short8*)&dst[(size_t)d * S_ + st0 + ch * 8] = o;
  }
}

// ---------------- RoPE table, interleaved (cos,sin) pairs ----------------
__global__ __launch_bounds__(256) void rope_table(float* __restrict__ cs) {
  int idx = blockIdx.x * 256 + threadIdx.x;   // 2048*64
  int pos = idx >> 6, i = idx & 63;
  float inv = powf(10000.f, -(float)i / 64.f);
  float a = (float)pos * inv;
  cs[idx * 2] = cosf(a);
  cs[idx * 2 + 1] = sinf(a);
}

// ---------------- GEMM: swapped-operand epilogue + optional fused RoPE ----------------
template <int OUTF32, int ROPE>
__global__ __launch_bounds__(256) void gemm_bt(const u16* __restrict__ A, int lda,
                                               const u16* __restrict__ BT,
                                               const float* __restrict__ bias,
                                               const float* __restrict__ cs,
                                               void* __restrict__ Cout,
                                               int M, int N, int K) {
  __shared__ u16 As[128 * 64];
  __shared__ u16 Bs[128 * 64];
  const int t = threadIdx.x;
  const int lane = t & 63, wave = t >> 6;
  const int wm = wave >> 1, wn = wave & 1;
  const int gx = gridDim.x;
  const int nwg = gx * gridDim.y;
  const int flat = blockIdx.y * gx + blockIdx.x;
  const int swz = (flat & 7) * (nwg >> 3) + (flat >> 3);
  const int tn = swz % gx, tm = swz / gx;
  const int r16 = lane & 15, q4 = lane >> 4;

  f32x4 acc[4][4];
#pragma unroll
  for (int m = 0; m < 4; ++m)
#pragma unroll
    for (int n = 0; n < 4; ++n) acc[m][n] = (f32x4){0.f, 0.f, 0.f, 0.f};

  for (int kt = 0; kt < K; kt += 64) {
#pragma unroll
    for (int c = 0; c < 4; ++c) {
      int idx = c * 256 + t;
      int row = idx >> 3, ch = idx & 7;
      gload16(&A[(size_t)(tm * 128 + row) * lda + kt + ch * 8], (char*)As + idx * 16);
      gload16(&BT[(size_t)(tn * 128 + row) * K + kt + ch * 8], (char*)Bs + idx * 16);
    }
    __syncthreads();
#pragma unroll
    for (int kk = 0; kk < 64; kk += 32) {
      short8 af[4], bfv[4];
#pragma unroll
      for (int m = 0; m < 4; ++m)
        af[m] = *(const short8*)&As[(wm * 64 + m * 16 + r16) * 64 + kk + q4 * 8];
#pragma unroll
      for (int n = 0; n < 4; ++n)
        bfv[n] = *(const short8*)&Bs[(wn * 64 + n * 16 + r16) * 64 + kk + q4 * 8];
      __builtin_amdgcn_s_setprio(1);
#pragma unroll
      for (int m = 0; m < 4; ++m)
#pragma unroll
        for (int n = 0; n < 4; ++n)
          acc[m][n] = __builtin_amdgcn_mfma_f32_16x16x32_bf16(bfv[n], af[m], acc[m][n], 0, 0, 0);
      __builtin_amdgcn_s_setprio(0);
    }
    __syncthreads();
  }
#pragma unroll
  for (int n = 0; n < 4; ++n) {
    int gc0 = tn * 128 + wn * 64 + n * 16 + q4 * 4;
    float4 bv4 = *(const float4*)&bias[gc0];
    const int i0 = (gc0 & 127) >> 1;
#pragma unroll
    for (int m = 0; m < 4; ++m) {
      int grow = tm * 128 + wm * 64 + m * 16 + r16;
      float v0 = acc[m][n][0] + bv4.x, v1 = acc[m][n][1] + bv4.y;
      float v2 = acc[m][n][2] + bv4.z, v3 = acc[m][n][3] + bv4.w;
      if (ROPE && gc0 < ROPE) {
        int s = grow & 2047;
        float4 cp = *(const float4*)&cs[((size_t)s * 64 + i0) * 2];   // c0,s0,c1,s1
        float y0 = v0 * cp.x - v1 * cp.y;
        float y1 = v0 * cp.y + v1 * cp.x;
        float y2 = v2 * cp.z - v3 * cp.w;
        float y3 = v2 * cp.w + v3 * cp.z;
        v0 = y0; v1 = y1; v2 = y2; v3 = y3;
      }
      if (OUTF32) {
        float4 o; o.x = v0; o.y = v1; o.z = v2; o.w = v3;
        *(float4*)&((float*)Cout)[(size_t)grow * N + gc0] = o;
      } else {
        u16x4 o; o.x = f2bf(v0); o.y = f2bf(v1); o.z = f2bf(v2); o.w = f2bf(v3);
        *(u16x4*)&((u16*)Cout)[(size_t)grow * N + gc0] = o;
      }
    }
  }
}

// ---------------- causal flash attention v8: 256 blocks, 128-row q-tiles, M=2 waves ----------------
// 256 blocks: xcd=b&7, r=b>>3, p=r&7, g=r>>3; bh=xcd+8g. Segments qt=p then qt=15-p
// (128-row q-tiles, 16 per head): exactly 34 KV-tiles per block; 1 block per CU
// (XCD round-robin on b&7, LDS 104KB caps residency at 1). 4 waves x 32 q-rows (M=2):
// each K/V LDS fragment feeds 2 MFMAs (halves the LDS-BW bottleneck vs 16-row waves).
__global__ __launch_bounds__(256, 1) void attn_kernel(const u16* __restrict__ Q, const u16* __restrict__ K,
                                                      int kld, const u16* __restrict__ VT,
                                                      u16* __restrict__ O) {
  __shared__ u16 Kl[2][KVB * 128];   // 16KB each, [kv][d] rows 256B, chunk^(row&7) swizzle
  __shared__ u16 Vl[2][128 * KVB];   // 16KB each, [d][kv] rows 128B, chunk^(row&7) swizzle
  __shared__ u16 Pl[4][40 * 64];     // per-wave P [q 32][kv 64] (+pad rows to pin 1 block/CU)
  const int t = threadIdx.x;
  const int lane = t & 63, w = t >> 6;
  const int r16 = lane & 15, q4 = lane >> 4;
  const int b = blockIdx.x;
  const int xcd = b & 7, r = b >> 3;
  const int p = r & 7, g = r >> 3;
  const int bh = xcd + 8 * g;
  const int bb = bh >> 4, h = bh & 15;
  const u16* Qb = Q + (size_t)bb * S_ * HID_ + (size_t)h * 128;
  const u16* Kb = K + (size_t)bb * S_ * kld + (size_t)h * 128;
  const u16* VTb = VT + (size_t)bh * 128 * S_;
  u16* Ob = O + (size_t)bb * S_ * HID_ + (size_t)h * 128;

  auto stage = [&](int buf, int kvbase) {
#pragma unroll
    for (int c = 0; c < 4; ++c) {
      int s = c * 256 + t;
      int row = s >> 4;
      int chs = (s & 15) ^ (row & 7);
      gload16(&Kb[(size_t)(kvbase + row) * kld + chs * 8], (char*)Kl[buf] + s * 16);
    }
#pragma unroll
    for (int c = 0; c < 4; ++c) {
      int s = c * 256 + t;
      int row = s >> 3;
      int chs = (s & 7) ^ (row & 7);
      gload16(&VTb[(size_t)row * S_ + kvbase + chs * 8], (char*)Vl[buf] + s * 16);
    }
  };

  u16* Pw = &Pl[w][0];
  const float SCALE = 0.08838834764831845f;

#pragma unroll
  for (int seg = 0; seg < 2; ++seg) {
    const int qt = seg ? (15 - p) : p;
    const int nt = 2 * qt + 2;
    const int qrow0 = qt * 128 + w * 32;      // wave's 32 q-rows

    short8 qf[2][4];
#pragma unroll
    for (int m = 0; m < 2; ++m)
#pragma unroll
      for (int dk = 0; dk < 4; ++dk)
        qf[m][dk] = *(const short8*)&Qb[(size_t)(qrow0 + m * 16 + r16) * HID_ + dk * 32 + q4 * 8];

    f32x4 ao[2][8];
    float mr[2], lr[2];
#pragma unroll
    for (int m = 0; m < 2; ++m) {
#pragma unroll
      for (int dn = 0; dn < 8; ++dn) ao[m][dn] = (f32x4){0.f, 0.f, 0.f, 0.f};
      mr[m] = -1e30f; lr[m] = 0.f;
    }

    stage(0, 0);
    __syncthreads();

    for (int ti = 0; ti < nt; ++ti) {
      const int buf = ti & 1;
      const int kv0 = ti * KVB;
      if (ti + 1 < nt) stage(buf ^ 1, kv0 + KVB);

      if (kv0 <= qrow0 + 31) {
        // ---- QK^T swapped: sc[m][n], col=q (r16 within m), row=kv ----
        f32x4 sc[2][4];
#pragma unroll
        for (int m = 0; m < 2; ++m)
#pragma unroll
          for (int n = 0; n < 4; ++n) sc[m][n] = (f32x4){0.f, 0.f, 0.f, 0.f};
#pragma unroll
        for (int dk = 0; dk < 4; ++dk) {
          short8 kf[4];
#pragma unroll
          for (int n = 0; n < 4; ++n) {
            int kr = n * 16 + r16;
            int ba = (kr * 256 + dk * 64 + q4 * 16) ^ ((kr & 7) << 4);
            kf[n] = *(const short8*)((const char*)Kl[buf] + ba);
          }
          __builtin_amdgcn_s_setprio(1);
#pragma unroll
          for (int n = 0; n < 4; ++n)
#pragma unroll
            for (int m = 0; m < 2; ++m)
              sc[m][n] = __builtin_amdgcn_mfma_f32_16x16x32_bf16(kf[n], qf[m][dk], sc[m][n], 0, 0, 0);
          __builtin_amdgcn_s_setprio(0);
        }
        // ---- scale + causal mask (kv > q masked) ----
        const bool nm = (kv0 + 63 > qrow0);
#pragma unroll
        for (int m = 0; m < 2; ++m) {
          const int q = qrow0 + m * 16 + r16;
#pragma unroll
          for (int n = 0; n < 4; ++n)
#pragma unroll
            for (int j = 0; j < 4; ++j) {
              float sv = sc[m][n][j] * SCALE;
              if (nm) {
                int kv = kv0 + n * 16 + q4 * 4 + j;
                if (kv > q) sv = -1e30f;
              }
              sc[m][n][j] = sv;
            }
        }
        // ---- online softmax per m (16 local + 2 shfl), joint defer-max ----
        float tm0[2];
#pragma unroll
        for (int m = 0; m < 2; ++m) {
          float tm = sc[m][0][0];
#pragma unroll
          for (int n = 0; n < 4; ++n)
#pragma unroll
            for (int j = 0; j < 4; ++j) tm = fmaxf(tm, sc[m][n][j]);
          tm = fmaxf(tm, __shfl_xor(tm, 16));
          tm = fmaxf(tm, __shfl_xor(tm, 32));
          tm0[m] = tm;
        }
        float growth = fmaxf(tm0[0] - mr[0], tm0[1] - mr[1]);
        if (!__all(growth <= 8.0f)) {
#pragma unroll
          for (int m = 0; m < 2; ++m) {
            float mnew = fmaxf(mr[m], tm0[m]);
            float fsc = __expf(mr[m] - mnew);
            lr[m] *= fsc; mr[m] = mnew;
#pragma unroll
            for (int dn = 0; dn < 8; ++dn) ao[m][dn] *= fsc;
          }
        }
#pragma unroll
        for (int m = 0; m < 2; ++m) {
          float ps = 0.f;
#pragma unroll
          for (int n = 0; n < 4; ++n)
#pragma unroll
            for (int j = 0; j < 4; ++j) {
              float pv = __expf(sc[m][n][j] - mr[m]);
              sc[m][n][j] = pv;
              ps += pv;
            }
          ps += __shfl_xor(ps, 16);
          ps += __shfl_xor(ps, 32);
          lr[m] += ps;
        }
        // ---- P -> LDS: cvt_pk, b64 writes; row = m*16+r16, 128B rows, ^(row&7)<<4 ----
#pragma unroll
        for (int m = 0; m < 2; ++m)
#pragma unroll
          for (int n = 0; n < 4; ++n) {
            u32 lo, hi;
            asm("v_cvt_pk_bf16_f32 %0, %1, %2" : "=v"(lo) : "v"(sc[m][n][0]), "v"(sc[m][n][1]));
            asm("v_cvt_pk_bf16_f32 %0, %1, %2" : "=v"(hi) : "v"(sc[m][n][2]), "v"(sc[m][n][3]));
            u32x2 pr; pr.x = lo; pr.y = hi;
            int ba = ((m * 16 + r16) * 128 + n * 32 + q4 * 8) ^ ((r16 & 7) << 4);
            *(u32x2*)((char*)Pw + ba) = pr;
          }
        // ---- PV: O^T = mfma(A=V^T-frag, B=P^T-frag); vf shared across m ----
#pragma unroll
        for (int s = 0; s < 2; ++s) {
          short8 pb[2];
#pragma unroll
          for (int m = 0; m < 2; ++m) {
            int ba = ((m * 16 + r16) * 128 + s * 64 + q4 * 16) ^ ((r16 & 7) << 4);
            pb[m] = *(const short8*)((const char*)Pw + ba);
          }
          __builtin_amdgcn_s_setprio(1);
#pragma unroll
          for (int dn = 0; dn < 8; ++dn) {
            int dr = dn * 16 + r16;
            int bv = (dr * 128 + s * 64 + q4 * 16) ^ ((dr & 7) << 4);
            short8 vf = *(const short8*)((const char*)Vl[buf] + bv);
#pragma unroll
            for (int m = 0; m < 2; ++m)
              ao[m][dn] = __builtin_amdgcn_mfma_f32_16x16x32_bf16(vf, pb[m], ao[m][dn], 0, 0, 0);
          }
          __builtin_amdgcn_s_setprio(0);
        }
      }
      __syncthreads();   // next tile's DMA landed; buffers safe to swap
    }

    // ---- epilogue: O[q][d] ----
#pragma unroll
    for (int m = 0; m < 2; ++m) {
      float inv = 1.f / lr[m];
      const int q = qrow0 + m * 16 + r16;
#pragma unroll
      for (int dn = 0; dn < 8; ++dn) {
        u16x4 o;
#pragma unroll
        for (int j = 0; j < 4; ++j) o[j] = f2bf(ao[m][dn][j] * inv);
        *(u16x4*)&Ob[(size_t)q * HID_ + dn * 16 + q4 * 4] = o;
      }
    }
    __syncthreads();   // segment boundary before restaging buf 0
  }
}

// ---------------- host launch ----------------
extern "C" void kernel_launch(void* const* d_in, const int* in_sizes, int n_in,
                              void* d_out, int out_size, void* d_ws, size_t ws_size,
                              hipStream_t stream) {
  (void)in_sizes; (void)n_in; (void)out_size; (void)ws_size;
  const float* x     = (const float*)d_in[0];
  const float* W_dkv = (const float*)d_in[2];
  const float* b_dkv = (const float*)d_in[3];
  const float* W_uk  = (const float*)d_in[4];
  const float* b_uk  = (const float*)d_in[5];
  const float* W_uv  = (const float*)d_in[6];
  const float* b_uv  = (const float*)d_in[7];
  const float* W_dq  = (const float*)d_in[8];
  const float* b_dq  = (const float*)d_in[9];
  const float* W_uq  = (const float*)d_in[10];
  const float* b_uq  = (const float*)d_in[11];
  const float* W_o   = (const float*)d_in[12];
  const float* b_o   = (const float*)d_in[13];
  float* out = (float*)d_out;

  char* ws = (char*)d_ws;
  size_t off = 0;
  auto carve = [&](size_t bytes) { void* p = ws + off; off += (bytes + 255) & ~(size_t)255; return p; };
  u16* xb     = (u16*)carve((size_t)BS_ * 2048 * 2);      // reused as VT after GEMM1
  u16* WdkvqT = (u16*)carve((size_t)2048 * 2048 * 2);     // rows 0-511 dkv, 512-2047 dq
  u16* WukvT  = (u16*)carve((size_t)4096 * 512 * 2);      // rows 0-2047 uk, 2048-4095 uv
  u16* WuqT   = (u16*)carve((size_t)2048 * 1536 * 2);
  u16* WoT    = (u16*)carve((size_t)2048 * 2048 * 2);
  u16* kvq1   = (u16*)carve((size_t)BS_ * 2048 * 2);      // cols 0-511 kv, 512-2047 q1
  u16* kvbuf  = (u16*)carve((size_t)BS_ * 4096 * 2);      // cols 0-2047 k(roped), 2048-4095 v
  u16* qb     = (u16*)carve((size_t)BS_ * 2048 * 2);
  u16* aob    = (u16*)carve((size_t)BS_ * 2048 * 2);
  float* cs   = (float*)carve((size_t)2048 * 64 * 2 * 4); // interleaved cos/sin
  float* bc1  = (float*)carve((size_t)2048 * 4);
  float* bc2  = (float*)carve((size_t)4096 * 4);
  u16* VT     = xb;   // xb dead after GEMM1

  conv_f2b<<<dim3(BS_ * 2048 / 4 / 256), 256, 0, stream>>>(x, xb, BS_ * 2048 / 4);
  transpose_conv<<<dim3(512 / 64, 2048 / 64), 256, 0, stream>>>(W_dkv, WdkvqT, 2048, 512);
  transpose_conv<<<dim3(1536 / 64, 2048 / 64), 256, 0, stream>>>(W_dq, WdkvqT + (size_t)512 * 2048, 2048, 1536);
  transpose_conv<<<dim3(2048 / 64, 512 / 64), 256, 0, stream>>>(W_uk, WukvT, 512, 2048);
  transpose_conv<<<dim3(2048 / 64, 512 / 64), 256, 0, stream>>>(W_uv, WukvT + (size_t)2048 * 512, 512, 2048);
  transpose_conv<<<dim3(2048 / 64, 1536 / 64), 256, 0, stream>>>(W_uq, WuqT, 1536, 2048);
  transpose_conv<<<dim3(2048 / 64, 2048 / 64), 256, 0, stream>>>(W_o, WoT, 2048, 2048);
  rope_table<<<dim3(512), 256, 0, stream>>>(cs);
  concat_bias<<<dim3(24), 256, 0, stream>>>(b_dkv, b_dq, b_uk, b_uv, bc1, bc2);

  // GEMM1: x @ {W_dkv|W_dq} -> kvq1
  gemm_bt<0, 0><<<dim3(2048 / 128, BS_ / 128), 256, 0, stream>>>(xb, 2048, WdkvqT, bc1, nullptr, kvq1, BS_, 2048, 2048);
  // GEMM2: kv @ {W_uk|W_uv} -> kvbuf, rope on k-cols (<2048)
  gemm_bt<0, 2048><<<dim3(4096 / 128, BS_ / 128), 256, 0, stream>>>(kvq1, 2048, WukvT, bc2, cs, kvbuf, BS_, 4096, 512);
  // GEMM3: q1 @ W_uq -> qb, rope on all cols
  gemm_bt<0, 2048><<<dim3(2048 / 128, BS_ / 128), 256, 0, stream>>>(kvq1 + 512, 2048, WuqT, b_uq, cs, qb, BS_, 2048, 1536);

  vtrans<<<dim3(S_ / 64, 32), 256, 0, stream>>>(kvbuf, VT);

  attn_kernel<<<dim3(256), 256, 0, stream>>>(qb, kvbuf, 4096, VT, aob);

  // GEMM4: attn_out @ W_o -> out (fp32)
  gemm_bt<1, 0><<<dim3(2048 / 128, BS_ / 128), 256, 0, stream>>>(aob, 2048, WoT, b_o, nullptr, out, BS_, 2048, 2048);
}

// Round 10
// 302.476 us; speedup vs baseline: 1.0516x; 1.0494x over previous
//
#include <hip/hip_runtime.h>
#include <stdint.h>

typedef unsigned short u16;
typedef uint32_t u32;
typedef __attribute__((ext_vector_type(8))) short short8;
typedef __attribute__((ext_vector_type(4))) float f32x4;
typedef __attribute__((ext_vector_type(4))) u32 u32x4;
typedef __attribute__((ext_vector_type(2))) u32 u32x2;
typedef __attribute__((ext_vector_type(4))) unsigned short u16x4;

#define BS_ 4096   // B*S rows
#define S_ 2048
#define HID_ 2048

__device__ __forceinline__ float bf2f(u16 u) { union { u32 i; float f; } v; v.i = ((u32)u) << 16; return v.f; }
__device__ __forceinline__ u16 f2bf(float f) {
  union { float f; u32 i; } v; v.f = f;
  u32 r = v.i + 0x7fffu + ((v.i >> 16) & 1u);
  return (u16)(r >> 16);
}

__device__ __forceinline__ void gload16(const void* gsrc, void* ldst) {
  __builtin_amdgcn_global_load_lds(
      (const __attribute__((address_space(1))) void*)gsrc,
      (__attribute__((address_space(3))) void*)ldst, 16, 0, 0);
}

// ---------------- elementwise convert fp32 -> bf16 ----------------
__global__ __launch_bounds__(256) void conv_f2b(const float* __restrict__ in, u16* __restrict__ out, int n4) {
  int i = blockIdx.x * 256 + threadIdx.x;
  if (i < n4) {
    float4 v = ((const float4*)in)[i];
    u16x4 o;
    o.x = f2bf(v.x); o.y = f2bf(v.y); o.z = f2bf(v.z); o.w = f2bf(v.w);
    ((u16x4*)out)[i] = o;
  }
}

// ---------------- transpose + convert: W[K][N] fp32 -> WT[N][K] bf16 ----------------
__global__ __launch_bounds__(256) void transpose_conv(const float* __restrict__ W, u16* __restrict__ WT,
                                                      int K, int N) {
  __shared__ float tile[64][65];
  const int t = threadIdx.x;
  const int kb = blockIdx.y * 64, nb = blockIdx.x * 64;
#pragma unroll
  for (int c = 0; c < 4; ++c) {
    int idx = c * 256 + t;
    int row = idx >> 4;
    int col4 = (idx & 15) * 4;
    float4 v = *(const float4*)&W[(size_t)(kb + row) * N + nb + col4];
    tile[row][col4 + 0] = v.x; tile[row][col4 + 1] = v.y;
    tile[row][col4 + 2] = v.z; tile[row][col4 + 3] = v.w;
  }
  __syncthreads();
#pragma unroll
  for (int c = 0; c < 4; ++c) {
    int idx = c * 256 + t;
    int n = idx >> 4;
    int k4 = (idx & 15) * 4;
    u16x4 o;
    o.x = f2bf(tile[k4 + 0][n]); o.y = f2bf(tile[k4 + 1][n]);
    o.z = f2bf(tile[k4 + 2][n]); o.w = f2bf(tile[k4 + 3][n]);
    *(u16x4*)&WT[(size_t)(nb + n) * K + kb + k4] = o;
  }
}

// ---------------- bias concat ----------------
__global__ __launch_bounds__(256) void concat_bias(const float* __restrict__ b_dkv, const float* __restrict__ b_dq,
                                                   const float* __restrict__ b_uk, const float* __restrict__ b_uv,
                                                   float* __restrict__ bc1, float* __restrict__ bc2) {
  int i = blockIdx.x * 256 + threadIdx.x;
  if (i < 512) bc1[i] = b_dkv[i];
  else if (i < 2048) bc1[i] = b_dq[i - 512];
  else if (i < 4096) bc2[i - 2048] = b_uk[i - 2048];
  else if (i < 6144) bc2[i - 2048] = b_uv[i - 4096];
}

// ---------------- V transpose: kvbuf[b][s][2048 + h*128 + d] -> VT[(b*16+h)][d][s] ----------------
__global__ __launch_bounds__(256) void vtrans(const u16* __restrict__ KVin, u16* __restrict__ VT) {
  __shared__ u16 tile[64][136];
  const int t = threadIdx.x;
  const int st0 = blockIdx.x * 64;
  const int bh = blockIdx.y;
  const int bb = bh >> 4, h = bh & 15;
  const u16* src = KVin + (size_t)bb * S_ * 4096 + 2048 + (size_t)h * 128;
  u16* dst = VT + (size_t)bh * 128 * S_;
#pragma unroll
  for (int c = 0; c < 4; ++c) {
    int idx = c * 256 + t;
    int s = idx >> 4, ch = idx & 15;
    short8 v = *(const short8*)&src[(size_t)(st0 + s) * 4096 + ch * 8];
    *(short8*)&tile[s][ch * 8] = v;
  }
  __syncthreads();
#pragma unroll
  for (int c = 0; c < 4; ++c) {
    int idx = c * 256 + t;
    int d = idx >> 3, ch = idx & 7;
    short8 o;
#pragma unroll
    for (int j = 0; j < 8; ++j) o[j] = tile[ch * 8 + j][d];
    *(short8*)&dst[(size_t)d * S_ + st0 + ch * 8] = o;
  }
}

// ---------------- RoPE table, interleaved (cos,sin) pairs ----------------
__global__ __launch_bounds__(256) void rope_table(float* __restrict__ cs) {
  int idx = blockIdx.x * 256 + threadIdx.x;   // 2048*64
  int pos = idx >> 6, i = idx & 63;
  float inv = powf(10000.f, -(float)i / 64.f);
  float a = (float)pos * inv;
  cs[idx * 2] = cosf(a);
  cs[idx * 2 + 1] = sinf(a);
}

// ---------------- GEMM: swapped-operand epilogue + optional fused RoPE ----------------
template <int OUTF32, int ROPE>
__global__ __launch_bounds__(256) void gemm_bt(const u16* __restrict__ A, int lda,
                                               const u16* __restrict__ BT,
                                               const float* __restrict__ bias,
                                               const float* __restrict__ cs,
                                               void* __restrict__ Cout,
                                               int M, int N, int K) {
  __shared__ u16 As[128 * 64];
  __shared__ u16 Bs[128 * 64];
  const int t = threadIdx.x;
  const int lane = t & 63, wave = t >> 6;
  const int wm = wave >> 1, wn = wave & 1;
  const int gx = gridDim.x;
  const int nwg = gx * gridDim.y;
  const int flat = blockIdx.y * gx + blockIdx.x;
  const int swz = (flat & 7) * (nwg >> 3) + (flat >> 3);
  const int tn = swz % gx, tm = swz / gx;
  const int r16 = lane & 15, q4 = lane >> 4;

  f32x4 acc[4][4];
#pragma unroll
  for (int m = 0; m < 4; ++m)
#pragma unroll
    for (int n = 0; n < 4; ++n) acc[m][n] = (f32x4){0.f, 0.f, 0.f, 0.f};

  for (int kt = 0; kt < K; kt += 64) {
#pragma unroll
    for (int c = 0; c < 4; ++c) {
      int idx = c * 256 + t;
      int row = idx >> 3, ch = idx & 7;
      gload16(&A[(size_t)(tm * 128 + row) * lda + kt + ch * 8], (char*)As + idx * 16);
      gload16(&BT[(size_t)(tn * 128 + row) * K + kt + ch * 8], (char*)Bs + idx * 16);
    }
    __syncthreads();
#pragma unroll
    for (int kk = 0; kk < 64; kk += 32) {
      short8 af[4], bfv[4];
#pragma unroll
      for (int m = 0; m < 4; ++m)
        af[m] = *(const short8*)&As[(wm * 64 + m * 16 + r16) * 64 + kk + q4 * 8];
#pragma unroll
      for (int n = 0; n < 4; ++n)
        bfv[n] = *(const short8*)&Bs[(wn * 64 + n * 16 + r16) * 64 + kk + q4 * 8];
      __builtin_amdgcn_s_setprio(1);
#pragma unroll
      for (int m = 0; m < 4; ++m)
#pragma unroll
        for (int n = 0; n < 4; ++n)
          acc[m][n] = __builtin_amdgcn_mfma_f32_16x16x32_bf16(bfv[n], af[m], acc[m][n], 0, 0, 0);
      __builtin_amdgcn_s_setprio(0);
    }
    __syncthreads();
  }
#pragma unroll
  for (int n = 0; n < 4; ++n) {
    int gc0 = tn * 128 + wn * 64 + n * 16 + q4 * 4;
    float4 bv4 = *(const float4*)&bias[gc0];
    const int i0 = (gc0 & 127) >> 1;
#pragma unroll
    for (int m = 0; m < 4; ++m) {
      int grow = tm * 128 + wm * 64 + m * 16 + r16;
      float v0 = acc[m][n][0] + bv4.x, v1 = acc[m][n][1] + bv4.y;
      float v2 = acc[m][n][2] + bv4.z, v3 = acc[m][n][3] + bv4.w;
      if (ROPE && gc0 < ROPE) {
        int s = grow & 2047;
        float4 cp = *(const float4*)&cs[((size_t)s * 64 + i0) * 2];   // c0,s0,c1,s1
        float y0 = v0 * cp.x - v1 * cp.y;
        float y1 = v0 * cp.y + v1 * cp.x;
        float y2 = v2 * cp.z - v3 * cp.w;
        float y3 = v2 * cp.w + v3 * cp.z;
        v0 = y0; v1 = y1; v2 = y2; v3 = y3;
      }
      if (OUTF32) {
        float4 o; o.x = v0; o.y = v1; o.z = v2; o.w = v3;
        *(float4*)&((float*)Cout)[(size_t)grow * N + gc0] = o;
      } else {
        u16x4 o; o.x = f2bf(v0); o.y = f2bf(v1); o.z = f2bf(v2); o.w = f2bf(v3);
        *(u16x4*)&((u16*)Cout)[(size_t)grow * N + gc0] = o;
      }
    }
  }
}

// ---------------- causal flash attention v9: kv-parity split, M=2 waves, in-block merge ----------------
// 512 blocks (2/CU): xcd=b&7, u=b>>3, p=u&15, g4=u>>4; bh=g4*8+xcd. Segments qt=p then 31-p
// (64-row q-tiles): per segment, waves {0,1} process even 32-kv tiles, waves {2,3} odd tiles,
// each wave covering 32 q-rows (M=2). nt=2qt+2 tiles -> qt+1 rounds, both parities equal work.
// Segment ends with LDS merge of the two parity partials (zero global traffic).
__global__ __launch_bounds__(256, 2) void attn_kernel(const u16* __restrict__ Q, const u16* __restrict__ K,
                                                      int kld, const u16* __restrict__ VT,
                                                      u16* __restrict__ O) {
  __shared__ char smem[75776];
  u16* Kl = (u16*)smem;             // 4 bufs x [32][128], chunk^(row&7)   (32 KB)
  u16* Vl = (u16*)(smem + 32768);   // 4 bufs x [128][32], chunk^((row>>1)&3) (32 KB)
  u16* Pl = (u16*)(smem + 65536);   // 4 waves x [32 rows][40 u16=80B]     (10 KB)
  float* ex = (float*)smem;         // merge overlay (34 KB, K/V dead then)

  const int t = threadIdx.x;
  const int lane = t & 63, w = t >> 6;
  const int r16 = lane & 15, q4 = lane >> 4;
  const int par = w >> 1, sub = w & 1;
  const int b = blockIdx.x;
  const int xcd = b & 7, u = b >> 3;
  const int p = u & 15, g4 = u >> 4;
  const int bh = g4 * 8 + xcd;
  const int bb = bh >> 4, h = bh & 15;
  const u16* Qb = Q + (size_t)bb * S_ * HID_ + (size_t)h * 128;
  const u16* Kb = K + (size_t)bb * S_ * kld + (size_t)h * 128;
  const u16* VTb = VT + (size_t)bh * 128 * S_;
  u16* Ob = O + (size_t)bb * S_ * HID_ + (size_t)h * 128;

  // stage both parities' tiles of one round into buffer set rs
  auto stage = [&](int rs, int kvbase) {
#pragma unroll
    for (int pp = 0; pp < 2; ++pp) {
      int kvb = kvbase + pp * 32;
      char* kd = (char*)(Kl + (size_t)(rs * 2 + pp) * 4096);
      char* vd = (char*)(Vl + (size_t)(rs * 2 + pp) * 4096);
#pragma unroll
      for (int c = 0; c < 2; ++c) {
        int s = c * 256 + t;
        int row = s >> 4;
        int ch = (s & 15) ^ (row & 7);
        gload16(&Kb[(size_t)(kvb + row) * kld + ch * 8], kd + s * 16);
      }
#pragma unroll
      for (int c = 0; c < 2; ++c) {
        int s = c * 256 + t;
        int row = s >> 2;
        int ch = (s & 3) ^ ((row >> 1) & 3);
        gload16(&VTb[(size_t)row * S_ + kvb + ch * 8], vd + s * 16);
      }
    }
  };

  u16* Pw = Pl + (size_t)w * 1280;
  const float SCALE = 0.08838834764831845f;

#pragma unroll
  for (int seg = 0; seg < 2; ++seg) {
    const int qt = seg ? (31 - p) : p;
    const int nr = qt + 1;                    // rounds (2 tiles each)
    const int qrow0 = qt * 64 + sub * 32;     // this wave's 32 q-rows

    short8 qf[2][4];
#pragma unroll
    for (int m = 0; m < 2; ++m)
#pragma unroll
      for (int dk = 0; dk < 4; ++dk)
        qf[m][dk] = *(const short8*)&Qb[(size_t)(qrow0 + m * 16 + r16) * HID_ + dk * 32 + q4 * 8];

    f32x4 ao[2][8];
    float mr[2], lr[2];
#pragma unroll
    for (int m = 0; m < 2; ++m) {
#pragma unroll
      for (int dn = 0; dn < 8; ++dn) ao[m][dn] = (f32x4){0.f, 0.f, 0.f, 0.f};
      mr[m] = -1e30f; lr[m] = 0.f;
    }

    stage(0, 0);
    __syncthreads();

    for (int r = 0; r < nr; ++r) {
      const int rs = r & 1;
      if (r + 1 < nr) stage(rs ^ 1, (r + 1) * 64);
      const int kv0 = r * 64 + par * 32;
      const u16* Kbuf = Kl + (size_t)(rs * 2 + par) * 4096;
      const u16* Vbuf = Vl + (size_t)(rs * 2 + par) * 4096;

      if (kv0 <= qrow0 + 31) {
        // ---- QK^T swapped: sc[m][n], col=q (r16), row=kv ----
        f32x4 sc[2][2];
#pragma unroll
        for (int m = 0; m < 2; ++m)
#pragma unroll
          for (int n = 0; n < 2; ++n) sc[m][n] = (f32x4){0.f, 0.f, 0.f, 0.f};
#pragma unroll
        for (int dk = 0; dk < 4; ++dk) {
          short8 kf[2];
#pragma unroll
          for (int n = 0; n < 2; ++n) {
            int kr = n * 16 + r16;
            int ba = (kr * 256 + dk * 64 + q4 * 16) ^ ((kr & 7) << 4);
            kf[n] = *(const short8*)((const char*)Kbuf + ba);
          }
          __builtin_amdgcn_s_setprio(1);
#pragma unroll
          for (int n = 0; n < 2; ++n)
#pragma unroll
            for (int m = 0; m < 2; ++m)
              sc[m][n] = __builtin_amdgcn_mfma_f32_16x16x32_bf16(kf[n], qf[m][dk], sc[m][n], 0, 0, 0);
          __builtin_amdgcn_s_setprio(0);
        }
        // ---- scale + causal mask ----
        const bool nm = (kv0 + 31 > qrow0);
#pragma unroll
        for (int m = 0; m < 2; ++m) {
          const int q = qrow0 + m * 16 + r16;
#pragma unroll
          for (int n = 0; n < 2; ++n)
#pragma unroll
            for (int j = 0; j < 4; ++j) {
              float sv = sc[m][n][j] * SCALE;
              if (nm) {
                int kv = kv0 + n * 16 + q4 * 4 + j;
                if (kv > q) sv = -1e30f;
              }
              sc[m][n][j] = sv;
            }
        }
        // ---- online softmax per m, joint defer-max ----
        float tm0[2];
#pragma unroll
        for (int m = 0; m < 2; ++m) {
          float tm = sc[m][0][0];
#pragma unroll
          for (int n = 0; n < 2; ++n)
#pragma unroll
            for (int j = 0; j < 4; ++j) tm = fmaxf(tm, sc[m][n][j]);
          tm = fmaxf(tm, __shfl_xor(tm, 16));
          tm = fmaxf(tm, __shfl_xor(tm, 32));
          tm0[m] = tm;
        }
        float growth = fmaxf(tm0[0] - mr[0], tm0[1] - mr[1]);
        if (!__all(growth <= 8.0f)) {
#pragma unroll
          for (int m = 0; m < 2; ++m) {
            float mnew = fmaxf(mr[m], tm0[m]);
            float fsc = __expf(mr[m] - mnew);
            lr[m] *= fsc; mr[m] = mnew;
#pragma unroll
            for (int dn = 0; dn < 8; ++dn) ao[m][dn] *= fsc;
          }
        }
#pragma unroll
        for (int m = 0; m < 2; ++m) {
          float ps = 0.f;
#pragma unroll
          for (int n = 0; n < 2; ++n)
#pragma unroll
            for (int j = 0; j < 4; ++j) {
              float pv = __expf(sc[m][n][j] - mr[m]);
              sc[m][n][j] = pv;
              ps += pv;
            }
          ps += __shfl_xor(ps, 16);
          ps += __shfl_xor(ps, 32);
          lr[m] += ps;
        }
        // ---- P -> LDS: [32 rows][80B padded rows] ----
#pragma unroll
        for (int m = 0; m < 2; ++m)
#pragma unroll
          for (int n = 0; n < 2; ++n) {
            u32 lo, hi;
            asm("v_cvt_pk_bf16_f32 %0, %1, %2" : "=v"(lo) : "v"(sc[m][n][0]), "v"(sc[m][n][1]));
            asm("v_cvt_pk_bf16_f32 %0, %1, %2" : "=v"(hi) : "v"(sc[m][n][2]), "v"(sc[m][n][3]));
            u32x2 pr; pr.x = lo; pr.y = hi;
            int ba = (m * 16 + r16) * 80 + n * 32 + q4 * 8;
            *(u32x2*)((char*)Pw + ba) = pr;
          }
        // ---- PV: O^T = mfma(A=V^T-frag, B=P-frag); vf shared across m ----
        short8 pb[2];
#pragma unroll
        for (int m = 0; m < 2; ++m)
          pb[m] = *(const short8*)((const char*)Pw + (m * 16 + r16) * 80 + q4 * 16);
        __builtin_amdgcn_s_setprio(1);
#pragma unroll
        for (int dn = 0; dn < 8; ++dn) {
          int d = dn * 16 + r16;
          int bv = d * 64 + ((q4 ^ ((d >> 1) & 3)) * 16);
          short8 vf = *(const short8*)((const char*)Vbuf + bv);
#pragma unroll
          for (int m = 0; m < 2; ++m)
            ao[m][dn] = __builtin_amdgcn_mfma_f32_16x16x32_bf16(vf, pb[m], ao[m][dn], 0, 0, 0);
        }
        __builtin_amdgcn_s_setprio(0);
      }
      __syncthreads();   // next round staged (drains vmcnt); buffers safe to swap
    }

    // ---- in-block merge of parity partials (waves 2,3 -> 0,1) ----
    {
      float* exb = ex + (size_t)sub * 4352 + (size_t)lane * 68;
      if (par == 1) {
#pragma unroll
        for (int m = 0; m < 2; ++m)
#pragma unroll
          for (int dn = 0; dn < 8; ++dn)
            *(f32x4*)(exb + m * 32 + dn * 4) = ao[m][dn];
        exb[64] = mr[0]; exb[65] = mr[1]; exb[66] = lr[0]; exb[67] = lr[1];
      }
      __syncthreads();
      if (par == 0) {
#pragma unroll
        for (int m = 0; m < 2; ++m) {
          float mB = exb[64 + m], lB = exb[66 + m];
          float mx = fmaxf(mr[m], mB);
          float wA = __expf(mr[m] - mx), wB = __expf(mB - mx);
          float inv = 1.f / (lr[m] * wA + lB * wB);
          const int q = qrow0 + m * 16 + r16;
#pragma unroll
          for (int dn = 0; dn < 8; ++dn) {
            f32x4 ob = *(const f32x4*)(exb + m * 32 + dn * 4);
            u16x4 o;
#pragma unroll
            for (int j = 0; j < 4; ++j) o[j] = f2bf((ao[m][dn][j] * wA + ob[j] * wB) * inv);
            *(u16x4*)&Ob[(size_t)q * HID_ + dn * 16 + q4 * 4] = o;
          }
        }
      }
      __syncthreads();   // merge read done before next segment restages
    }
  }
}

// ---------------- host launch ----------------
extern "C" void kernel_launch(void* const* d_in, const int* in_sizes, int n_in,
                              void* d_out, int out_size, void* d_ws, size_t ws_size,
                              hipStream_t stream) {
  (void)in_sizes; (void)n_in; (void)out_size; (void)ws_size;
  const float* x     = (const float*)d_in[0];
  const float* W_dkv = (const float*)d_in[2];
  const float* b_dkv = (const float*)d_in[3];
  const float* W_uk  = (const float*)d_in[4];
  const float* b_uk  = (const float*)d_in[5];
  const float* W_uv  = (const float*)d_in[6];
  const float* b_uv  = (const float*)d_in[7];
  const float* W_dq  = (const float*)d_in[8];
  const float* b_dq  = (const float*)d_in[9];
  const float* W_uq  = (const float*)d_in[10];
  const float* b_uq  = (const float*)d_in[11];
  const float* W_o   = (const float*)d_in[12];
  const float* b_o   = (const float*)d_in[13];
  float* out = (float*)d_out;

  char* ws = (char*)d_ws;
  size_t off = 0;
  auto carve = [&](size_t bytes) { void* p = ws + off; off += (bytes + 255) & ~(size_t)255; return p; };
  u16* xb     = (u16*)carve((size_t)BS_ * 2048 * 2);      // reused as VT after GEMM1
  u16* WdkvqT = (u16*)carve((size_t)2048 * 2048 * 2);     // rows 0-511 dkv, 512-2047 dq
  u16* WukvT  = (u16*)carve((size_t)4096 * 512 * 2);      // rows 0-2047 uk, 2048-4095 uv
  u16* WuqT   = (u16*)carve((size_t)2048 * 1536 * 2);
  u16* WoT    = (u16*)carve((size_t)2048 * 2048 * 2);
  u16* kvq1   = (u16*)carve((size_t)BS_ * 2048 * 2);      // cols 0-511 kv, 512-2047 q1
  u16* kvbuf  = (u16*)carve((size_t)BS_ * 4096 * 2);      // cols 0-2047 k(roped), 2048-4095 v
  u16* qb     = (u16*)carve((size_t)BS_ * 2048 * 2);
  u16* aob    = (u16*)carve((size_t)BS_ * 2048 * 2);
  float* cs   = (float*)carve((size_t)2048 * 64 * 2 * 4); // interleaved cos/sin
  float* bc1  = (float*)carve((size_t)2048 * 4);
  float* bc2  = (float*)carve((size_t)4096 * 4);
  u16* VT     = xb;   // xb dead after GEMM1

  conv_f2b<<<dim3(BS_ * 2048 / 4 / 256), 256, 0, stream>>>(x, xb, BS_ * 2048 / 4);
  transpose_conv<<<dim3(512 / 64, 2048 / 64), 256, 0, stream>>>(W_dkv, WdkvqT, 2048, 512);
  transpose_conv<<<dim3(1536 / 64, 2048 / 64), 256, 0, stream>>>(W_dq, WdkvqT + (size_t)512 * 2048, 2048, 1536);
  transpose_conv<<<dim3(2048 / 64, 512 / 64), 256, 0, stream>>>(W_uk, WukvT, 512, 2048);
  transpose_conv<<<dim3(2048 / 64, 512 / 64), 256, 0, stream>>>(W_uv, WukvT + (size_t)2048 * 512, 512, 2048);
  transpose_conv<<<dim3(2048 / 64, 1536 / 64), 256, 0, stream>>>(W_uq, WuqT, 1536, 2048);
  transpose_conv<<<dim3(2048 / 64, 2048 / 64), 256, 0, stream>>>(W_o, WoT, 2048, 2048);
  rope_table<<<dim3(512), 256, 0, stream>>>(cs);
  concat_bias<<<dim3(24), 256, 0, stream>>>(b_dkv, b_dq, b_uk, b_uv, bc1, bc2);

  // GEMM1: x @ {W_dkv|W_dq} -> kvq1
  gemm_bt<0, 0><<<dim3(2048 / 128, BS_ / 128), 256, 0, stream>>>(xb, 2048, WdkvqT, bc1, nullptr, kvq1, BS_, 2048, 2048);
  // GEMM2: kv @ {W_uk|W_uv} -> kvbuf, rope on k-cols (<2048)
  gemm_bt<0, 2048><<<dim3(4096 / 128, BS_ / 128), 256, 0, stream>>>(kvq1, 2048, WukvT, bc2, cs, kvbuf, BS_, 4096, 512);
  // GEMM3: q1 @ W_uq -> qb, rope on all cols
  gemm_bt<0, 2048><<<dim3(2048 / 128, BS_ / 128), 256, 0, stream>>>(kvq1 + 512, 2048, WuqT, b_uq, cs, qb, BS_, 2048, 1536);

  vtrans<<<dim3(S_ / 64, 32), 256, 0, stream>>>(kvbuf, VT);

  attn_kernel<<<dim3(512), 256, 0, stream>>>(qb, kvbuf, 4096, VT, aob);

  // GEMM4: attn_out @ W_o -> out (fp32)
  gemm_bt<1, 0><<<dim3(2048 / 128, BS_ / 128), 256, 0, stream>>>(aob, 2048, WoT, b_o, nullptr, out, BS_, 2048, 2048);
}

// Round 11
// 271.273 us; speedup vs baseline: 1.1725x; 1.1150x over previous
//
#include <hip/hip_runtime.h>
#include <stdint.h>

typedef unsigned short u16;
typedef uint32_t u32;
typedef __attribute__((ext_vector_type(8))) short short8;
typedef __attribute__((ext_vector_type(4))) float f32x4;
typedef __attribute__((ext_vector_type(4))) u32 u32x4;
typedef __attribute__((ext_vector_type(2))) u32 u32x2;
typedef __attribute__((ext_vector_type(4))) unsigned short u16x4;

#define BS_ 4096   // B*S rows
#define S_ 2048
#define HID_ 2048

__device__ __forceinline__ float bf2f(u16 u) { union { u32 i; float f; } v; v.i = ((u32)u) << 16; return v.f; }
__device__ __forceinline__ u16 f2bf(float f) {
  union { float f; u32 i; } v; v.f = f;
  u32 r = v.i + 0x7fffu + ((v.i >> 16) & 1u);
  return (u16)(r >> 16);
}

__device__ __forceinline__ void gload16(const void* gsrc, void* ldst) {
  __builtin_amdgcn_global_load_lds(
      (const __attribute__((address_space(1))) void*)gsrc,
      (__attribute__((address_space(3))) void*)ldst, 16, 0, 0);
}

// ---------------- fused prep: x->bf16, 6 weight transposes, rope table, bias concat ----------------
// grid: 8192 (f2b) + 3328 (transposes) + 512 (rope) + 24 (bias) = 12056 blocks
__global__ __launch_bounds__(256) void prep(const float* __restrict__ x, u16* __restrict__ xb,
                                            const float* __restrict__ W_dkv, const float* __restrict__ W_dq,
                                            const float* __restrict__ W_uk, const float* __restrict__ W_uv,
                                            const float* __restrict__ W_uq, const float* __restrict__ W_o,
                                            u16* __restrict__ WdkvqT, u16* __restrict__ WukvT,
                                            u16* __restrict__ WuqT, u16* __restrict__ WoT,
                                            const float* __restrict__ b_dkv, const float* __restrict__ b_dq,
                                            const float* __restrict__ b_uk, const float* __restrict__ b_uv,
                                            float* __restrict__ cs, float* __restrict__ bc1,
                                            float* __restrict__ bc2) {
  __shared__ float tile[64][65];
  int b = blockIdx.x;
  const int t = threadIdx.x;
  if (b < 8192) {                       // fp32 -> bf16 convert of x
    int i = b * 256 + t;
    float4 v = ((const float4*)x)[i];
    u16x4 o;
    o.x = f2bf(v.x); o.y = f2bf(v.y); o.z = f2bf(v.z); o.w = f2bf(v.w);
    ((u16x4*)xb)[i] = o;
    return;
  }
  b -= 8192;
  if (b < 3328) {                       // weight transpose+convert: W[K][N] -> WT[N][K]
    const float* W; u16* WT; int K, N, gx, r = b;
    if (r < 256)                 { W = W_dkv; WT = WdkvqT;                    K = 2048; N = 512;  gx = 8;  }
    else if ((r -= 256) < 768)   { W = W_dq;  WT = WdkvqT + (size_t)512 * 2048; K = 2048; N = 1536; gx = 24; }
    else if ((r -= 768) < 256)   { W = W_uk;  WT = WukvT;                     K = 512;  N = 2048; gx = 32; }
    else if ((r -= 256) < 256)   { W = W_uv;  WT = WukvT + (size_t)2048 * 512;  K = 512;  N = 2048; gx = 32; }
    else if ((r -= 256) < 768)   { W = W_uq;  WT = WuqT;                      K = 1536; N = 2048; gx = 32; }
    else                         { r -= 768;  W = W_o; WT = WoT;              K = 2048; N = 2048; gx = 32; }
    const int nb = (r % gx) * 64, kb = (r / gx) * 64;
#pragma unroll
    for (int c = 0; c < 4; ++c) {
      int idx = c * 256 + t;
      int row = idx >> 4;
      int col4 = (idx & 15) * 4;
      float4 v = *(const float4*)&W[(size_t)(kb + row) * N + nb + col4];
      tile[row][col4 + 0] = v.x; tile[row][col4 + 1] = v.y;
      tile[row][col4 + 2] = v.z; tile[row][col4 + 3] = v.w;
    }
    __syncthreads();
#pragma unroll
    for (int c = 0; c < 4; ++c) {
      int idx = c * 256 + t;
      int n = idx >> 4;
      int k4 = (idx & 15) * 4;
      u16x4 o;
      o.x = f2bf(tile[k4 + 0][n]); o.y = f2bf(tile[k4 + 1][n]);
      o.z = f2bf(tile[k4 + 2][n]); o.w = f2bf(tile[k4 + 3][n]);
      *(u16x4*)&WT[(size_t)(nb + n) * K + kb + k4] = o;
    }
    return;
  }
  b -= 3328;
  if (b < 512) {                        // rope table, interleaved (cos,sin)
    int idx = b * 256 + t;
    int pos = idx >> 6, i = idx & 63;
    float inv = powf(10000.f, -(float)i / 64.f);
    float a = (float)pos * inv;
    cs[idx * 2] = cosf(a);
    cs[idx * 2 + 1] = sinf(a);
    return;
  }
  b -= 512;
  {                                     // bias concat
    int i = b * 256 + t;
    if (i < 512) bc1[i] = b_dkv[i];
    else if (i < 2048) bc1[i] = b_dq[i - 512];
    else if (i < 4096) bc2[i - 2048] = b_uk[i - 2048];
    else if (i < 6144) bc2[i - 2048] = b_uv[i - 4096];
  }
}

// ---------------- GEMM (m97-structure, swapped-operand epilogue, XCD swizzle) ----------------
template <int OUTF32>
__global__ __launch_bounds__(256) void gemm_bt(const u16* __restrict__ A, int lda,
                                               const u16* __restrict__ BT,
                                               const float* __restrict__ bias,
                                               void* __restrict__ Cout,
                                               int M, int N, int K) {
  __shared__ u16 As[128 * 64];
  __shared__ u16 Bs[128 * 64];
  const int t = threadIdx.x;
  const int lane = t & 63, wave = t >> 6;
  const int wm = wave >> 1, wn = wave & 1;
  const int gx = gridDim.x;
  const int nwg = gx * gridDim.y;
  const int flat = blockIdx.y * gx + blockIdx.x;
  const int swz = (flat & 7) * (nwg >> 3) + (flat >> 3);
  const int tn = swz % gx, tm = swz / gx;
  const int r16 = lane & 15, q4 = lane >> 4;

  f32x4 acc[4][4];
#pragma unroll
  for (int m = 0; m < 4; ++m)
#pragma unroll
    for (int n = 0; n < 4; ++n) acc[m][n] = (f32x4){0.f, 0.f, 0.f, 0.f};

  for (int kt = 0; kt < K; kt += 64) {
#pragma unroll
    for (int c = 0; c < 4; ++c) {
      int idx = c * 256 + t;
      int row = idx >> 3, ch = idx & 7;
      gload16(&A[(size_t)(tm * 128 + row) * lda + kt + ch * 8], (char*)As + idx * 16);
      gload16(&BT[(size_t)(tn * 128 + row) * K + kt + ch * 8], (char*)Bs + idx * 16);
    }
    __syncthreads();
#pragma unroll
    for (int kk = 0; kk < 64; kk += 32) {
      short8 af[4], bfv[4];
#pragma unroll
      for (int m = 0; m < 4; ++m)
        af[m] = *(const short8*)&As[(wm * 64 + m * 16 + r16) * 64 + kk + q4 * 8];
#pragma unroll
      for (int n = 0; n < 4; ++n)
        bfv[n] = *(const short8*)&Bs[(wn * 64 + n * 16 + r16) * 64 + kk + q4 * 8];
      __builtin_amdgcn_s_setprio(1);
#pragma unroll
      for (int m = 0; m < 4; ++m)
#pragma unroll
        for (int n = 0; n < 4; ++n)
          acc[m][n] = __builtin_amdgcn_mfma_f32_16x16x32_bf16(bfv[n], af[m], acc[m][n], 0, 0, 0);
      __builtin_amdgcn_s_setprio(0);
    }
    __syncthreads();
  }
#pragma unroll
  for (int n = 0; n < 4; ++n) {
    int gc0 = tn * 128 + wn * 64 + n * 16 + q4 * 4;
    float4 bv4 = *(const float4*)&bias[gc0];
#pragma unroll
    for (int m = 0; m < 4; ++m) {
      int grow = tm * 128 + wm * 64 + m * 16 + r16;
      float v0 = acc[m][n][0] + bv4.x, v1 = acc[m][n][1] + bv4.y;
      float v2 = acc[m][n][2] + bv4.z, v3 = acc[m][n][3] + bv4.w;
      if (OUTF32) {
        float4 o; o.x = v0; o.y = v1; o.z = v2; o.w = v3;
        *(float4*)&((float*)Cout)[(size_t)grow * N + gc0] = o;
      } else {
        u16x4 o; o.x = f2bf(v0); o.y = f2bf(v1); o.z = f2bf(v2); o.w = f2bf(v3);
        *(u16x4*)&((u16*)Cout)[(size_t)grow * N + gc0] = o;
      }
    }
  }
}

// ---------------- merged GEMM2+GEMM3 with fused RoPE and fused V-transpose ----------------
// blocks 0..1023:  GEMM2: kvq1[:, :512] @ {W_uk|W_uv} (K=512, N=4096)
//    tn<16 (k-half): rope + store kbuf [4096][2048]
//    tn>=16 (v-half): no rope, store transposed into VT[(b*16+h)][d][s]
// blocks 1024..1535: GEMM3: kvq1[:, 512:] @ W_uq (K=1536, N=2048), rope, store qb
__global__ __launch_bounds__(256) void gemm23(const u16* __restrict__ kvq1,
                                              const u16* __restrict__ WukvT, const u16* __restrict__ WuqT,
                                              const float* __restrict__ bc2, const float* __restrict__ b_uq,
                                              const float* __restrict__ cs,
                                              u16* __restrict__ kbuf, u16* __restrict__ VT,
                                              u16* __restrict__ qb) {
  __shared__ u16 As[128 * 64];
  __shared__ u16 Bs[128 * 64];
  const int t = threadIdx.x;
  const int lane = t & 63, wave = t >> 6;
  const int wm = wave >> 1, wn = wave & 1;
  const int bflat = blockIdx.x;
  const bool g2 = (bflat < 1024);
  const u16* A  = g2 ? kvq1 : (kvq1 + 512);
  const u16* BT = g2 ? WukvT : WuqT;
  const float* bias = g2 ? bc2 : b_uq;
  const int N = g2 ? 4096 : 2048;
  const int K = g2 ? 512 : 1536;
  const int gx = g2 ? 32 : 16;
  const int nwg = g2 ? 1024 : 512;
  const int flat = g2 ? bflat : (bflat - 1024);
  const int swz = (flat & 7) * (nwg >> 3) + (flat >> 3);
  const int tn = swz % gx, tm = swz / gx;
  const int r16 = lane & 15, q4 = lane >> 4;

  f32x4 acc[4][4];
#pragma unroll
  for (int m = 0; m < 4; ++m)
#pragma unroll
    for (int n = 0; n < 4; ++n) acc[m][n] = (f32x4){0.f, 0.f, 0.f, 0.f};

  for (int kt = 0; kt < K; kt += 64) {
#pragma unroll
    for (int c = 0; c < 4; ++c) {
      int idx = c * 256 + t;
      int row = idx >> 3, ch = idx & 7;
      gload16(&A[(size_t)(tm * 128 + row) * 2048 + kt + ch * 8], (char*)As + idx * 16);
      gload16(&BT[(size_t)(tn * 128 + row) * K + kt + ch * 8], (char*)Bs + idx * 16);
    }
    __syncthreads();
#pragma unroll
    for (int kk = 0; kk < 64; kk += 32) {
      short8 af[4], bfv[4];
#pragma unroll
      for (int m = 0; m < 4; ++m)
        af[m] = *(const short8*)&As[(wm * 64 + m * 16 + r16) * 64 + kk + q4 * 8];
#pragma unroll
      for (int n = 0; n < 4; ++n)
        bfv[n] = *(const short8*)&Bs[(wn * 64 + n * 16 + r16) * 64 + kk + q4 * 8];
      __builtin_amdgcn_s_setprio(1);
#pragma unroll
      for (int m = 0; m < 4; ++m)
#pragma unroll
        for (int n = 0; n < 4; ++n)
          acc[m][n] = __builtin_amdgcn_mfma_f32_16x16x32_bf16(bfv[n], af[m], acc[m][n], 0, 0, 0);
      __builtin_amdgcn_s_setprio(0);
    }
    __syncthreads();
  }

  const bool isV = g2 && (tn >= 16);
  u16* outp = g2 ? kbuf : qb;
#pragma unroll
  for (int n = 0; n < 4; ++n) {
    int gc0 = tn * 128 + wn * 64 + n * 16 + q4 * 4;
    float4 bv4 = *(const float4*)&bias[gc0];
    const int i0 = (gc0 & 127) >> 1;
#pragma unroll
    for (int m = 0; m < 4; ++m) {
      int grow = tm * 128 + wm * 64 + m * 16 + r16;
      float v0 = acc[m][n][0] + bv4.x, v1 = acc[m][n][1] + bv4.y;
      float v2 = acc[m][n][2] + bv4.z, v3 = acc[m][n][3] + bv4.w;
      if (!isV) {
        // rope (all cols here are < 2048)
        int s = grow & 2047;
        float4 cp = *(const float4*)&cs[((size_t)s * 64 + i0) * 2];   // c0,s0,c1,s1
        float y0 = v0 * cp.x - v1 * cp.y;
        float y1 = v0 * cp.y + v1 * cp.x;
        float y2 = v2 * cp.z - v3 * cp.w;
        float y3 = v2 * cp.w + v3 * cp.z;
        u16x4 o; o.x = f2bf(y0); o.y = f2bf(y1); o.z = f2bf(y2); o.w = f2bf(y3);
        *(u16x4*)&outp[(size_t)grow * 2048 + gc0] = o;
      } else {
        // transposed V store: VT[(bb*16+h)][d][s]
        int gcv = gc0 - 2048;
        int hh = gcv >> 7, d0 = gcv & 127;
        int bb = grow >> 11, s = grow & 2047;
        u16* vdst = VT + ((size_t)(bb * 16 + hh) * 128 + d0) * S_ + s;
        vdst[0]        = f2bf(v0);
        vdst[S_]       = f2bf(v1);
        vdst[2 * S_]   = f2bf(v2);
        vdst[3 * S_]   = f2bf(v3);
      }
    }
  }
}

// ---------------- causal flash attention v9 (unchanged): kv-parity split, in-block merge ----------------
__global__ __launch_bounds__(256, 2) void attn_kernel(const u16* __restrict__ Q, const u16* __restrict__ K,
                                                      int kld, const u16* __restrict__ VT,
                                                      u16* __restrict__ O) {
  __shared__ char smem[75776];
  u16* Kl = (u16*)smem;             // 4 bufs x [32][128], chunk^(row&7)   (32 KB)
  u16* Vl = (u16*)(smem + 32768);   // 4 bufs x [128][32], chunk^((row>>1)&3) (32 KB)
  u16* Pl = (u16*)(smem + 65536);   // 4 waves x [32 rows][80B]            (10 KB)
  float* ex = (float*)smem;         // merge overlay (K/V dead then)

  const int t = threadIdx.x;
  const int lane = t & 63, w = t >> 6;
  const int r16 = lane & 15, q4 = lane >> 4;
  const int par = w >> 1, sub = w & 1;
  const int b = blockIdx.x;
  const int xcd = b & 7, u = b >> 3;
  const int p = u & 15, g4 = u >> 4;
  const int bh = g4 * 8 + xcd;
  const int bb = bh >> 4, h = bh & 15;
  const u16* Qb = Q + (size_t)bb * S_ * HID_ + (size_t)h * 128;
  const u16* Kb = K + (size_t)bb * S_ * kld + (size_t)h * 128;
  const u16* VTb = VT + (size_t)bh * 128 * S_;
  u16* Ob = O + (size_t)bb * S_ * HID_ + (size_t)h * 128;

  auto stage = [&](int rs, int kvbase) {
#pragma unroll
    for (int pp = 0; pp < 2; ++pp) {
      int kvb = kvbase + pp * 32;
      char* kd = (char*)(Kl + (size_t)(rs * 2 + pp) * 4096);
      char* vd = (char*)(Vl + (size_t)(rs * 2 + pp) * 4096);
#pragma unroll
      for (int c = 0; c < 2; ++c) {
        int s = c * 256 + t;
        int row = s >> 4;
        int ch = (s & 15) ^ (row & 7);
        gload16(&Kb[(size_t)(kvb + row) * kld + ch * 8], kd + s * 16);
      }
#pragma unroll
      for (int c = 0; c < 2; ++c) {
        int s = c * 256 + t;
        int row = s >> 2;
        int ch = (s & 3) ^ ((row >> 1) & 3);
        gload16(&VTb[(size_t)row * S_ + kvb + ch * 8], vd + s * 16);
      }
    }
  };

  u16* Pw = Pl + (size_t)w * 1280;
  const float SCALE = 0.08838834764831845f;

#pragma unroll
  for (int seg = 0; seg < 2; ++seg) {
    const int qt = seg ? (31 - p) : p;
    const int nr = qt + 1;
    const int qrow0 = qt * 64 + sub * 32;

    short8 qf[2][4];
#pragma unroll
    for (int m = 0; m < 2; ++m)
#pragma unroll
      for (int dk = 0; dk < 4; ++dk)
        qf[m][dk] = *(const short8*)&Qb[(size_t)(qrow0 + m * 16 + r16) * HID_ + dk * 32 + q4 * 8];

    f32x4 ao[2][8];
    float mr[2], lr[2];
#pragma unroll
    for (int m = 0; m < 2; ++m) {
#pragma unroll
      for (int dn = 0; dn < 8; ++dn) ao[m][dn] = (f32x4){0.f, 0.f, 0.f, 0.f};
      mr[m] = -1e30f; lr[m] = 0.f;
    }

    stage(0, 0);
    __syncthreads();

    for (int r = 0; r < nr; ++r) {
      const int rs = r & 1;
      if (r + 1 < nr) stage(rs ^ 1, (r + 1) * 64);
      const int kv0 = r * 64 + par * 32;
      const u16* Kbuf = Kl + (size_t)(rs * 2 + par) * 4096;
      const u16* Vbuf = Vl + (size_t)(rs * 2 + par) * 4096;

      if (kv0 <= qrow0 + 31) {
        f32x4 sc[2][2];
#pragma unroll
        for (int m = 0; m < 2; ++m)
#pragma unroll
          for (int n = 0; n < 2; ++n) sc[m][n] = (f32x4){0.f, 0.f, 0.f, 0.f};
#pragma unroll
        for (int dk = 0; dk < 4; ++dk) {
          short8 kf[2];
#pragma unroll
          for (int n = 0; n < 2; ++n) {
            int kr = n * 16 + r16;
            int ba = (kr * 256 + dk * 64 + q4 * 16) ^ ((kr & 7) << 4);
            kf[n] = *(const short8*)((const char*)Kbuf + ba);
          }
          __builtin_amdgcn_s_setprio(1);
#pragma unroll
          for (int n = 0; n < 2; ++n)
#pragma unroll
            for (int m = 0; m < 2; ++m)
              sc[m][n] = __builtin_amdgcn_mfma_f32_16x16x32_bf16(kf[n], qf[m][dk], sc[m][n], 0, 0, 0);
          __builtin_amdgcn_s_setprio(0);
        }
        const bool nm = (kv0 + 31 > qrow0);
#pragma unroll
        for (int m = 0; m < 2; ++m) {
          const int q = qrow0 + m * 16 + r16;
#pragma unroll
          for (int n = 0; n < 2; ++n)
#pragma unroll
            for (int j = 0; j < 4; ++j) {
              float sv = sc[m][n][j] * SCALE;
              if (nm) {
                int kv = kv0 + n * 16 + q4 * 4 + j;
                if (kv > q) sv = -1e30f;
              }
              sc[m][n][j] = sv;
            }
        }
        float tm0[2];
#pragma unroll
        for (int m = 0; m < 2; ++m) {
          float tm = sc[m][0][0];
#pragma unroll
          for (int n = 0; n < 2; ++n)
#pragma unroll
            for (int j = 0; j < 4; ++j) tm = fmaxf(tm, sc[m][n][j]);
          tm = fmaxf(tm, __shfl_xor(tm, 16));
          tm = fmaxf(tm, __shfl_xor(tm, 32));
          tm0[m] = tm;
        }
        float growth = fmaxf(tm0[0] - mr[0], tm0[1] - mr[1]);
        if (!__all(growth <= 8.0f)) {
#pragma unroll
          for (int m = 0; m < 2; ++m) {
            float mnew = fmaxf(mr[m], tm0[m]);
            float fsc = __expf(mr[m] - mnew);
            lr[m] *= fsc; mr[m] = mnew;
#pragma unroll
            for (int dn = 0; dn < 8; ++dn) ao[m][dn] *= fsc;
          }
        }
#pragma unroll
        for (int m = 0; m < 2; ++m) {
          float ps = 0.f;
#pragma unroll
          for (int n = 0; n < 2; ++n)
#pragma unroll
            for (int j = 0; j < 4; ++j) {
              float pv = __expf(sc[m][n][j] - mr[m]);
              sc[m][n][j] = pv;
              ps += pv;
            }
          ps += __shfl_xor(ps, 16);
          ps += __shfl_xor(ps, 32);
          lr[m] += ps;
        }
#pragma unroll
        for (int m = 0; m < 2; ++m)
#pragma unroll
          for (int n = 0; n < 2; ++n) {
            u32 lo, hi;
            asm("v_cvt_pk_bf16_f32 %0, %1, %2" : "=v"(lo) : "v"(sc[m][n][0]), "v"(sc[m][n][1]));
            asm("v_cvt_pk_bf16_f32 %0, %1, %2" : "=v"(hi) : "v"(sc[m][n][2]), "v"(sc[m][n][3]));
            u32x2 pr; pr.x = lo; pr.y = hi;
            int ba = (m * 16 + r16) * 80 + n * 32 + q4 * 8;
            *(u32x2*)((char*)Pw + ba) = pr;
          }
        short8 pb[2];
#pragma unroll
        for (int m = 0; m < 2; ++m)
          pb[m] = *(const short8*)((const char*)Pw + (m * 16 + r16) * 80 + q4 * 16);
        __builtin_amdgcn_s_setprio(1);
#pragma unroll
        for (int dn = 0; dn < 8; ++dn) {
          int d = dn * 16 + r16;
          int bv = d * 64 + ((q4 ^ ((d >> 1) & 3)) * 16);
          short8 vf = *(const short8*)((const char*)Vbuf + bv);
#pragma unroll
          for (int m = 0; m < 2; ++m)
            ao[m][dn] = __builtin_amdgcn_mfma_f32_16x16x32_bf16(vf, pb[m], ao[m][dn], 0, 0, 0);
        }
        __builtin_amdgcn_s_setprio(0);
      }
      __syncthreads();
    }

    {
      float* exb = ex + (size_t)sub * 4352 + (size_t)lane * 68;
      if (par == 1) {
#pragma unroll
        for (int m = 0; m < 2; ++m)
#pragma unroll
          for (int dn = 0; dn < 8; ++dn)
            *(f32x4*)(exb + m * 32 + dn * 4) = ao[m][dn];
        exb[64] = mr[0]; exb[65] = mr[1]; exb[66] = lr[0]; exb[67] = lr[1];
      }
      __syncthreads();
      if (par == 0) {
#pragma unroll
        for (int m = 0; m < 2; ++m) {
          float mB = exb[64 + m], lB = exb[66 + m];
          float mx = fmaxf(mr[m], mB);
          float wA = __expf(mr[m] - mx), wB = __expf(mB - mx);
          float inv = 1.f / (lr[m] * wA + lB * wB);
          const int q = qrow0 + m * 16 + r16;
#pragma unroll
          for (int dn = 0; dn < 8; ++dn) {
            f32x4 ob = *(const f32x4*)(exb + m * 32 + dn * 4);
            u16x4 o;
#pragma unroll
            for (int j = 0; j < 4; ++j) o[j] = f2bf((ao[m][dn][j] * wA + ob[j] * wB) * inv);
            *(u16x4*)&Ob[(size_t)q * HID_ + dn * 16 + q4 * 4] = o;
          }
        }
      }
      __syncthreads();
    }
  }
}

// ---------------- host launch ----------------
extern "C" void kernel_launch(void* const* d_in, const int* in_sizes, int n_in,
                              void* d_out, int out_size, void* d_ws, size_t ws_size,
                              hipStream_t stream) {
  (void)in_sizes; (void)n_in; (void)out_size; (void)ws_size;
  const float* x     = (const float*)d_in[0];
  const float* W_dkv = (const float*)d_in[2];
  const float* b_dkv = (const float*)d_in[3];
  const float* W_uk  = (const float*)d_in[4];
  const float* b_uk  = (const float*)d_in[5];
  const float* W_uv  = (const float*)d_in[6];
  const float* b_uv  = (const float*)d_in[7];
  const float* W_dq  = (const float*)d_in[8];
  const float* b_dq  = (const float*)d_in[9];
  const float* W_uq  = (const float*)d_in[10];
  const float* b_uq  = (const float*)d_in[11];
  const float* W_o   = (const float*)d_in[12];
  const float* b_o   = (const float*)d_in[13];
  float* out = (float*)d_out;

  char* ws = (char*)d_ws;
  size_t off = 0;
  auto carve = [&](size_t bytes) { void* p = ws + off; off += (bytes + 255) & ~(size_t)255; return p; };
  u16* xb     = (u16*)carve((size_t)BS_ * 2048 * 2);      // reused as VT after GEMM1
  u16* WdkvqT = (u16*)carve((size_t)2048 * 2048 * 2);     // rows 0-511 dkv, 512-2047 dq
  u16* WukvT  = (u16*)carve((size_t)4096 * 512 * 2);      // rows 0-2047 uk, 2048-4095 uv
  u16* WuqT   = (u16*)carve((size_t)2048 * 1536 * 2);
  u16* WoT    = (u16*)carve((size_t)2048 * 2048 * 2);
  u16* kvq1   = (u16*)carve((size_t)BS_ * 2048 * 2);      // cols 0-511 kv, 512-2047 q1
  u16* kbuf   = (u16*)carve((size_t)BS_ * 2048 * 2);      // roped k [4096][2048]
  u16* qb     = (u16*)carve((size_t)BS_ * 2048 * 2);
  u16* aob    = (u16*)carve((size_t)BS_ * 2048 * 2);
  float* cs   = (float*)carve((size_t)2048 * 64 * 2 * 4); // interleaved cos/sin
  float* bc1  = (float*)carve((size_t)2048 * 4);
  float* bc2  = (float*)carve((size_t)4096 * 4);
  u16* VT     = xb;   // xb dead after GEMM1; V^T [32][128][2048]

  prep<<<dim3(12056), 256, 0, stream>>>(x, xb, W_dkv, W_dq, W_uk, W_uv, W_uq, W_o,
                                        WdkvqT, WukvT, WuqT, WoT,
                                        b_dkv, b_dq, b_uk, b_uv, cs, bc1, bc2);

  // GEMM1: x @ {W_dkv|W_dq} -> kvq1
  gemm_bt<0><<<dim3(2048 / 128, BS_ / 128), 256, 0, stream>>>(xb, 2048, WdkvqT, bc1, kvq1, BS_, 2048, 2048);

  // GEMM2+GEMM3 merged: k (roped) -> kbuf, V^T -> VT, q (roped) -> qb
  gemm23<<<dim3(1536), 256, 0, stream>>>(kvq1, WukvT, WuqT, bc2, b_uq, cs, kbuf, VT, qb);

  attn_kernel<<<dim3(512), 256, 0, stream>>>(qb, kbuf, 2048, VT, aob);

  // GEMM4: attn_out @ W_o -> out (fp32)
  gemm_bt<1><<<dim3(2048 / 128, BS_ / 128), 256, 0, stream>>>(aob, 2048, WoT, b_o, out, BS_, 2048, 2048);
}

// Round 12
// 267.709 us; speedup vs baseline: 1.1881x; 1.0133x over previous
//
#include <hip/hip_runtime.h>
#include <stdint.h>

typedef unsigned short u16;
typedef uint32_t u32;
typedef __attribute__((ext_vector_type(8))) short short8;
typedef __attribute__((ext_vector_type(4))) float f32x4;
typedef __attribute__((ext_vector_type(4))) u32 u32x4;
typedef __attribute__((ext_vector_type(2))) u32 u32x2;
typedef __attribute__((ext_vector_type(4))) unsigned short u16x4;

#define BS_ 4096   // B*S rows
#define S_ 2048
#define HID_ 2048

__device__ __forceinline__ float bf2f(u16 u) { union { u32 i; float f; } v; v.i = ((u32)u) << 16; return v.f; }
__device__ __forceinline__ u16 f2bf(float f) {
  union { float f; u32 i; } v; v.f = f;
  u32 r = v.i + 0x7fffu + ((v.i >> 16) & 1u);
  return (u16)(r >> 16);
}

__device__ __forceinline__ void gload16(const void* gsrc, void* ldst) {
  __builtin_amdgcn_global_load_lds(
      (const __attribute__((address_space(1))) void*)gsrc,
      (__attribute__((address_space(3))) void*)ldst, 16, 0, 0);
}

// ---------------- fused prep: x->bf16, 6 weight transposes, rope table, bias concat ----------------
__global__ __launch_bounds__(256) void prep(const float* __restrict__ x, u16* __restrict__ xb,
                                            const float* __restrict__ W_dkv, const float* __restrict__ W_dq,
                                            const float* __restrict__ W_uk, const float* __restrict__ W_uv,
                                            const float* __restrict__ W_uq, const float* __restrict__ W_o,
                                            u16* __restrict__ WdkvqT, u16* __restrict__ WukvT,
                                            u16* __restrict__ WuqT, u16* __restrict__ WoT,
                                            const float* __restrict__ b_dkv, const float* __restrict__ b_dq,
                                            const float* __restrict__ b_uk, const float* __restrict__ b_uv,
                                            float* __restrict__ cs, float* __restrict__ bc1,
                                            float* __restrict__ bc2) {
  __shared__ float tile[64][65];
  int b = blockIdx.x;
  const int t = threadIdx.x;
  if (b < 8192) {
    int i = b * 256 + t;
    float4 v = ((const float4*)x)[i];
    u16x4 o;
    o.x = f2bf(v.x); o.y = f2bf(v.y); o.z = f2bf(v.z); o.w = f2bf(v.w);
    ((u16x4*)xb)[i] = o;
    return;
  }
  b -= 8192;
  if (b < 3328) {
    const float* W; u16* WT; int K, N, gx, r = b;
    if (r < 256)                 { W = W_dkv; WT = WdkvqT;                    K = 2048; N = 512;  gx = 8;  }
    else if ((r -= 256) < 768)   { W = W_dq;  WT = WdkvqT + (size_t)512 * 2048; K = 2048; N = 1536; gx = 24; }
    else if ((r -= 768) < 256)   { W = W_uk;  WT = WukvT;                     K = 512;  N = 2048; gx = 32; }
    else if ((r -= 256) < 256)   { W = W_uv;  WT = WukvT + (size_t)2048 * 512;  K = 512;  N = 2048; gx = 32; }
    else if ((r -= 256) < 768)   { W = W_uq;  WT = WuqT;                      K = 1536; N = 2048; gx = 32; }
    else                         { r -= 768;  W = W_o; WT = WoT;              K = 2048; N = 2048; gx = 32; }
    const int nb = (r % gx) * 64, kb = (r / gx) * 64;
#pragma unroll
    for (int c = 0; c < 4; ++c) {
      int idx = c * 256 + t;
      int row = idx >> 4;
      int col4 = (idx & 15) * 4;
      float4 v = *(const float4*)&W[(size_t)(kb + row) * N + nb + col4];
      tile[row][col4 + 0] = v.x; tile[row][col4 + 1] = v.y;
      tile[row][col4 + 2] = v.z; tile[row][col4 + 3] = v.w;
    }
    __syncthreads();
#pragma unroll
    for (int c = 0; c < 4; ++c) {
      int idx = c * 256 + t;
      int n = idx >> 4;
      int k4 = (idx & 15) * 4;
      u16x4 o;
      o.x = f2bf(tile[k4 + 0][n]); o.y = f2bf(tile[k4 + 1][n]);
      o.z = f2bf(tile[k4 + 2][n]); o.w = f2bf(tile[k4 + 3][n]);
      *(u16x4*)&WT[(size_t)(nb + n) * K + kb + k4] = o;
    }
    return;
  }
  b -= 3328;
  if (b < 512) {
    int idx = b * 256 + t;
    int pos = idx >> 6, i = idx & 63;
    float inv = powf(10000.f, -(float)i / 64.f);
    float a = (float)pos * inv;
    cs[idx * 2] = cosf(a);
    cs[idx * 2 + 1] = sinf(a);
    return;
  }
  b -= 512;
  {
    int i = b * 256 + t;
    if (i < 512) bc1[i] = b_dkv[i];
    else if (i < 2048) bc1[i] = b_dq[i - 512];
    else if (i < 4096) bc2[i - 2048] = b_uk[i - 2048];
    else if (i < 6144) bc2[i - 2048] = b_uv[i - 4096];
  }
}

// ---------------- GEMM (double-buffered single-barrier K-loop, swapped epilogue, XCD swizzle) ----------------
template <int OUTF32>
__global__ __launch_bounds__(256) void gemm_bt(const u16* __restrict__ A, int lda,
                                               const u16* __restrict__ BT,
                                               const float* __restrict__ bias,
                                               void* __restrict__ Cout,
                                               int M, int N, int K) {
  __shared__ u16 As[2][128 * 64];
  __shared__ u16 Bs[2][128 * 64];
  const int t = threadIdx.x;
  const int lane = t & 63, wave = t >> 6;
  const int wm = wave >> 1, wn = wave & 1;
  const int gx = gridDim.x;
  const int nwg = gx * gridDim.y;
  const int flat = blockIdx.y * gx + blockIdx.x;
  const int swz = (flat & 7) * (nwg >> 3) + (flat >> 3);
  const int tn = swz % gx, tm = swz / gx;
  const int r16 = lane & 15, q4 = lane >> 4;

  f32x4 acc[4][4];
#pragma unroll
  for (int m = 0; m < 4; ++m)
#pragma unroll
    for (int n = 0; n < 4; ++n) acc[m][n] = (f32x4){0.f, 0.f, 0.f, 0.f};

  auto stg = [&](int bufi, int kt) {
#pragma unroll
    for (int c = 0; c < 4; ++c) {
      int idx = c * 256 + t;
      int row = idx >> 3, ch = idx & 7;
      gload16(&A[(size_t)(tm * 128 + row) * lda + kt + ch * 8], (char*)As[bufi] + idx * 16);
      gload16(&BT[(size_t)(tn * 128 + row) * K + kt + ch * 8], (char*)Bs[bufi] + idx * 16);
    }
  };

  const int nkt = K >> 6;
  stg(0, 0);
  __syncthreads();
  for (int it = 0; it < nkt; ++it) {
    const int buf = it & 1;
    if (it + 1 < nkt) stg(buf ^ 1, (it + 1) << 6);
#pragma unroll
    for (int kk = 0; kk < 64; kk += 32) {
      short8 af[4], bfv[4];
#pragma unroll
      for (int m = 0; m < 4; ++m)
        af[m] = *(const short8*)&As[buf][(wm * 64 + m * 16 + r16) * 64 + kk + q4 * 8];
#pragma unroll
      for (int n = 0; n < 4; ++n)
        bfv[n] = *(const short8*)&Bs[buf][(wn * 64 + n * 16 + r16) * 64 + kk + q4 * 8];
      __builtin_amdgcn_s_setprio(1);
#pragma unroll
      for (int m = 0; m < 4; ++m)
#pragma unroll
        for (int n = 0; n < 4; ++n)
          acc[m][n] = __builtin_amdgcn_mfma_f32_16x16x32_bf16(bfv[n], af[m], acc[m][n], 0, 0, 0);
      __builtin_amdgcn_s_setprio(0);
    }
    __syncthreads();
  }
#pragma unroll
  for (int n = 0; n < 4; ++n) {
    int gc0 = tn * 128 + wn * 64 + n * 16 + q4 * 4;
    float4 bv4 = *(const float4*)&bias[gc0];
#pragma unroll
    for (int m = 0; m < 4; ++m) {
      int grow = tm * 128 + wm * 64 + m * 16 + r16;
      float v0 = acc[m][n][0] + bv4.x, v1 = acc[m][n][1] + bv4.y;
      float v2 = acc[m][n][2] + bv4.z, v3 = acc[m][n][3] + bv4.w;
      if (OUTF32) {
        float4 o; o.x = v0; o.y = v1; o.z = v2; o.w = v3;
        *(float4*)&((float*)Cout)[(size_t)grow * N + gc0] = o;
      } else {
        u16x4 o; o.x = f2bf(v0); o.y = f2bf(v1); o.z = f2bf(v2); o.w = f2bf(v3);
        *(u16x4*)&((u16*)Cout)[(size_t)grow * N + gc0] = o;
      }
    }
  }
}

// ---------------- merged GEMM2+GEMM3 with fused RoPE and coalesced fused V-transpose ----------------
// blocks 0..1023:  GEMM2: kvq1[:, :512] @ {W_uk|W_uv} (K=512, N=4096)
//    tn<16 (k-half): rope + store kbuf; tn>=16 (v-half): LDS-transpose -> coalesced VT store
// blocks 1024..1535: GEMM3: kvq1[:, 512:] @ W_uq (K=1536, N=2048), rope, store qb
__global__ __launch_bounds__(256) void gemm23(const u16* __restrict__ kvq1,
                                              const u16* __restrict__ WukvT, const u16* __restrict__ WuqT,
                                              const float* __restrict__ bc2, const float* __restrict__ b_uq,
                                              const float* __restrict__ cs,
                                              u16* __restrict__ kbuf, u16* __restrict__ VT,
                                              u16* __restrict__ qb) {
  __shared__ u16 sh[2 * 128 * 64];   // As = sh, Bs = sh+8192; reused as 128x128 transpose buffer
  u16* As = sh;
  u16* Bs = sh + 8192;
  const int t = threadIdx.x;
  const int lane = t & 63, wave = t >> 6;
  const int wm = wave >> 1, wn = wave & 1;
  const int bflat = blockIdx.x;
  const bool g2 = (bflat < 1024);
  const u16* A  = g2 ? kvq1 : (kvq1 + 512);
  const u16* BT = g2 ? WukvT : WuqT;
  const float* bias = g2 ? bc2 : b_uq;
  const int K = g2 ? 512 : 1536;
  const int gx = g2 ? 32 : 16;
  const int nwg = g2 ? 1024 : 512;
  const int flat = g2 ? bflat : (bflat - 1024);
  const int swz = (flat & 7) * (nwg >> 3) + (flat >> 3);
  const int tn = swz % gx, tm = swz / gx;
  const int r16 = lane & 15, q4 = lane >> 4;

  f32x4 acc[4][4];
#pragma unroll
  for (int m = 0; m < 4; ++m)
#pragma unroll
    for (int n = 0; n < 4; ++n) acc[m][n] = (f32x4){0.f, 0.f, 0.f, 0.f};

  for (int kt = 0; kt < K; kt += 64) {
#pragma unroll
    for (int c = 0; c < 4; ++c) {
      int idx = c * 256 + t;
      int row = idx >> 3, ch = idx & 7;
      gload16(&A[(size_t)(tm * 128 + row) * 2048 + kt + ch * 8], (char*)As + idx * 16);
      gload16(&BT[(size_t)(tn * 128 + row) * K + kt + ch * 8], (char*)Bs + idx * 16);
    }
    __syncthreads();
#pragma unroll
    for (int kk = 0; kk < 64; kk += 32) {
      short8 af[4], bfv[4];
#pragma unroll
      for (int m = 0; m < 4; ++m)
        af[m] = *(const short8*)&As[(wm * 64 + m * 16 + r16) * 64 + kk + q4 * 8];
#pragma unroll
      for (int n = 0; n < 4; ++n)
        bfv[n] = *(const short8*)&Bs[(wn * 64 + n * 16 + r16) * 64 + kk + q4 * 8];
      __builtin_amdgcn_s_setprio(1);
#pragma unroll
      for (int m = 0; m < 4; ++m)
#pragma unroll
        for (int n = 0; n < 4; ++n)
          acc[m][n] = __builtin_amdgcn_mfma_f32_16x16x32_bf16(bfv[n], af[m], acc[m][n], 0, 0, 0);
      __builtin_amdgcn_s_setprio(0);
    }
    __syncthreads();
  }

  const bool isV = g2 && (tn >= 16);
  if (!isV) {
    u16* outp = g2 ? kbuf : qb;
#pragma unroll
    for (int n = 0; n < 4; ++n) {
      int gc0 = tn * 128 + wn * 64 + n * 16 + q4 * 4;
      float4 bv4 = *(const float4*)&bias[gc0];
      const int i0 = (gc0 & 127) >> 1;
#pragma unroll
      for (int m = 0; m < 4; ++m) {
        int grow = tm * 128 + wm * 64 + m * 16 + r16;
        float v0 = acc[m][n][0] + bv4.x, v1 = acc[m][n][1] + bv4.y;
        float v2 = acc[m][n][2] + bv4.z, v3 = acc[m][n][3] + bv4.w;
        int s = grow & 2047;
        float4 cp = *(const float4*)&cs[((size_t)s * 64 + i0) * 2];   // c0,s0,c1,s1
        float y0 = v0 * cp.x - v1 * cp.y;
        float y1 = v0 * cp.y + v1 * cp.x;
        float y2 = v2 * cp.z - v3 * cp.w;
        float y3 = v2 * cp.w + v3 * cp.z;
        u16x4 o; o.x = f2bf(y0); o.y = f2bf(y1); o.z = f2bf(y2); o.w = f2bf(y3);
        *(u16x4*)&outp[(size_t)grow * 2048 + gc0] = o;
      }
    }
  } else {
    // LDS transpose: lt[d][s] (128x128 u16, s XOR-swizzled by (d&7)<<4), then coalesced VT store
    u16* lt = sh;
#pragma unroll
    for (int n = 0; n < 4; ++n) {
      int gc0 = tn * 128 + wn * 64 + n * 16 + q4 * 4;
      float4 bv4 = *(const float4*)&bias[gc0];
      int dL0 = wn * 64 + n * 16 + q4 * 4;
#pragma unroll
      for (int m = 0; m < 4; ++m) {
        int sL = wm * 64 + m * 16 + r16;
        float vv[4] = {acc[m][n][0] + bv4.x, acc[m][n][1] + bv4.y,
                       acc[m][n][2] + bv4.z, acc[m][n][3] + bv4.w};
#pragma unroll
        for (int j = 0; j < 4; ++j) {
          int dd = dL0 + j;
          lt[dd * 128 + (sL ^ ((dd & 7) << 4))] = f2bf(vv[j]);
        }
      }
    }
    __syncthreads();
    const int hh = tn - 16;
    const int bb2 = tm >> 4;
    const int s0 = (tm & 15) * 128;
    u16* vbase = VT + (size_t)(bb2 * 16 + hh) * 128 * S_ + s0;
#pragma unroll
    for (int c = 0; c < 8; ++c) {
      int idx = c * 256 + t;
      int d = idx >> 4, ch = idx & 15;
      short8 v = *(const short8*)&lt[d * 128 + ((ch * 8) ^ ((d & 7) << 4))];
      *(short8*)&vbase[(size_t)d * S_ + ch * 8] = v;
    }
  }
}

// ---------------- causal flash attention v9 (unchanged): kv-parity split, in-block merge ----------------
__global__ __launch_bounds__(256, 2) void attn_kernel(const u16* __restrict__ Q, const u16* __restrict__ K,
                                                      int kld, const u16* __restrict__ VT,
                                                      u16* __restrict__ O) {
  __shared__ char smem[75776];
  u16* Kl = (u16*)smem;
  u16* Vl = (u16*)(smem + 32768);
  u16* Pl = (u16*)(smem + 65536);
  float* ex = (float*)smem;

  const int t = threadIdx.x;
  const int lane = t & 63, w = t >> 6;
  const int r16 = lane & 15, q4 = lane >> 4;
  const int par = w >> 1, sub = w & 1;
  const int b = blockIdx.x;
  const int xcd = b & 7, u = b >> 3;
  const int p = u & 15, g4 = u >> 4;
  const int bh = g4 * 8 + xcd;
  const int bb = bh >> 4, h = bh & 15;
  const u16* Qb = Q + (size_t)bb * S_ * HID_ + (size_t)h * 128;
  const u16* Kb = K + (size_t)bb * S_ * kld + (size_t)h * 128;
  const u16* VTb = VT + (size_t)bh * 128 * S_;
  u16* Ob = O + (size_t)bb * S_ * HID_ + (size_t)h * 128;

  auto stage = [&](int rs, int kvbase) {
#pragma unroll
    for (int pp = 0; pp < 2; ++pp) {
      int kvb = kvbase + pp * 32;
      char* kd = (char*)(Kl + (size_t)(rs * 2 + pp) * 4096);
      char* vd = (char*)(Vl + (size_t)(rs * 2 + pp) * 4096);
#pragma unroll
      for (int c = 0; c < 2; ++c) {
        int s = c * 256 + t;
        int row = s >> 4;
        int ch = (s & 15) ^ (row & 7);
        gload16(&Kb[(size_t)(kvb + row) * kld + ch * 8], kd + s * 16);
      }
#pragma unroll
      for (int c = 0; c < 2; ++c) {
        int s = c * 256 + t;
        int row = s >> 2;
        int ch = (s & 3) ^ ((row >> 1) & 3);
        gload16(&VTb[(size_t)row * S_ + kvb + ch * 8], vd + s * 16);
      }
    }
  };

  u16* Pw = Pl + (size_t)w * 1280;
  const float SCALE = 0.08838834764831845f;

#pragma unroll
  for (int seg = 0; seg < 2; ++seg) {
    const int qt = seg ? (31 - p) : p;
    const int nr = qt + 1;
    const int qrow0 = qt * 64 + sub * 32;

    short8 qf[2][4];
#pragma unroll
    for (int m = 0; m < 2; ++m)
#pragma unroll
      for (int dk = 0; dk < 4; ++dk)
        qf[m][dk] = *(const short8*)&Qb[(size_t)(qrow0 + m * 16 + r16) * HID_ + dk * 32 + q4 * 8];

    f32x4 ao[2][8];
    float mr[2], lr[2];
#pragma unroll
    for (int m = 0; m < 2; ++m) {
#pragma unroll
      for (int dn = 0; dn < 8; ++dn) ao[m][dn] = (f32x4){0.f, 0.f, 0.f, 0.f};
      mr[m] = -1e30f; lr[m] = 0.f;
    }

    stage(0, 0);
    __syncthreads();

    for (int r = 0; r < nr; ++r) {
      const int rs = r & 1;
      if (r + 1 < nr) stage(rs ^ 1, (r + 1) * 64);
      const int kv0 = r * 64 + par * 32;
      const u16* Kbuf = Kl + (size_t)(rs * 2 + par) * 4096;
      const u16* Vbuf = Vl + (size_t)(rs * 2 + par) * 4096;

      if (kv0 <= qrow0 + 31) {
        f32x4 sc[2][2];
#pragma unroll
        for (int m = 0; m < 2; ++m)
#pragma unroll
          for (int n = 0; n < 2; ++n) sc[m][n] = (f32x4){0.f, 0.f, 0.f, 0.f};
#pragma unroll
        for (int dk = 0; dk < 4; ++dk) {
          short8 kf[2];
#pragma unroll
          for (int n = 0; n < 2; ++n) {
            int kr = n * 16 + r16;
            int ba = (kr * 256 + dk * 64 + q4 * 16) ^ ((kr & 7) << 4);
            kf[n] = *(const short8*)((const char*)Kbuf + ba);
          }
          __builtin_amdgcn_s_setprio(1);
#pragma unroll
          for (int n = 0; n < 2; ++n)
#pragma unroll
            for (int m = 0; m < 2; ++m)
              sc[m][n] = __builtin_amdgcn_mfma_f32_16x16x32_bf16(kf[n], qf[m][dk], sc[m][n], 0, 0, 0);
          __builtin_amdgcn_s_setprio(0);
        }
        const bool nm = (kv0 + 31 > qrow0);
#pragma unroll
        for (int m = 0; m < 2; ++m) {
          const int q = qrow0 + m * 16 + r16;
#pragma unroll
          for (int n = 0; n < 2; ++n)
#pragma unroll
            for (int j = 0; j < 4; ++j) {
              float sv = sc[m][n][j] * SCALE;
              if (nm) {
                int kv = kv0 + n * 16 + q4 * 4 + j;
                if (kv > q) sv = -1e30f;
              }
              sc[m][n][j] = sv;
            }
        }
        float tm0[2];
#pragma unroll
        for (int m = 0; m < 2; ++m) {
          float tm = sc[m][0][0];
#pragma unroll
          for (int n = 0; n < 2; ++n)
#pragma unroll
            for (int j = 0; j < 4; ++j) tm = fmaxf(tm, sc[m][n][j]);
          tm = fmaxf(tm, __shfl_xor(tm, 16));
          tm = fmaxf(tm, __shfl_xor(tm, 32));
          tm0[m] = tm;
        }
        float growth = fmaxf(tm0[0] - mr[0], tm0[1] - mr[1]);
        if (!__all(growth <= 8.0f)) {
#pragma unroll
          for (int m = 0; m < 2; ++m) {
            float mnew = fmaxf(mr[m], tm0[m]);
            float fsc = __expf(mr[m] - mnew);
            lr[m] *= fsc; mr[m] = mnew;
#pragma unroll
            for (int dn = 0; dn < 8; ++dn) ao[m][dn] *= fsc;
          }
        }
#pragma unroll
        for (int m = 0; m < 2; ++m) {
          float ps = 0.f;
#pragma unroll
          for (int n = 0; n < 2; ++n)
#pragma unroll
            for (int j = 0; j < 4; ++j) {
              float pv = __expf(sc[m][n][j] - mr[m]);
              sc[m][n][j] = pv;
              ps += pv;
            }
          ps += __shfl_xor(ps, 16);
          ps += __shfl_xor(ps, 32);
          lr[m] += ps;
        }
#pragma unroll
        for (int m = 0; m < 2; ++m)
#pragma unroll
          for (int n = 0; n < 2; ++n) {
            u32 lo, hi;
            asm("v_cvt_pk_bf16_f32 %0, %1, %2" : "=v"(lo) : "v"(sc[m][n][0]), "v"(sc[m][n][1]));
            asm("v_cvt_pk_bf16_f32 %0, %1, %2" : "=v"(hi) : "v"(sc[m][n][2]), "v"(sc[m][n][3]));
            u32x2 pr; pr.x = lo; pr.y = hi;
            int ba = (m * 16 + r16) * 80 + n * 32 + q4 * 8;
            *(u32x2*)((char*)Pw + ba) = pr;
          }
        short8 pb[2];
#pragma unroll
        for (int m = 0; m < 2; ++m)
          pb[m] = *(const short8*)((const char*)Pw + (m * 16 + r16) * 80 + q4 * 16);
        __builtin_amdgcn_s_setprio(1);
#pragma unroll
        for (int dn = 0; dn < 8; ++dn) {
          int d = dn * 16 + r16;
          int bv = d * 64 + ((q4 ^ ((d >> 1) & 3)) * 16);
          short8 vf = *(const short8*)((const char*)Vbuf + bv);
#pragma unroll
          for (int m = 0; m < 2; ++m)
            ao[m][dn] = __builtin_amdgcn_mfma_f32_16x16x32_bf16(vf, pb[m], ao[m][dn], 0, 0, 0);
        }
        __builtin_amdgcn_s_setprio(0);
      }
      __syncthreads();
    }

    {
      float* exb = ex + (size_t)sub * 4352 + (size_t)lane * 68;
      if (par == 1) {
#pragma unroll
        for (int m = 0; m < 2; ++m)
#pragma unroll
          for (int dn = 0; dn < 8; ++dn)
            *(f32x4*)(exb + m * 32 + dn * 4) = ao[m][dn];
        exb[64] = mr[0]; exb[65] = mr[1]; exb[66] = lr[0]; exb[67] = lr[1];
      }
      __syncthreads();
      if (par == 0) {
#pragma unroll
        for (int m = 0; m < 2; ++m) {
          float mB = exb[64 + m], lB = exb[66 + m];
          float mx = fmaxf(mr[m], mB);
          float wA = __expf(mr[m] - mx), wB = __expf(mB - mx);
          float inv = 1.f / (lr[m] * wA + lB * wB);
          const int q = qrow0 + m * 16 + r16;
#pragma unroll
          for (int dn = 0; dn < 8; ++dn) {
            f32x4 ob = *(const f32x4*)(exb + m * 32 + dn * 4);
            u16x4 o;
#pragma unroll
            for (int j = 0; j < 4; ++j) o[j] = f2bf((ao[m][dn][j] * wA + ob[j] * wB) * inv);
            *(u16x4*)&Ob[(size_t)q * HID_ + dn * 16 + q4 * 4] = o;
          }
        }
      }
      __syncthreads();
    }
  }
}

// ---------------- host launch ----------------
extern "C" void kernel_launch(void* const* d_in, const int* in_sizes, int n_in,
                              void* d_out, int out_size, void* d_ws, size_t ws_size,
                              hipStream_t stream) {
  (void)in_sizes; (void)n_in; (void)out_size; (void)ws_size;
  const float* x     = (const float*)d_in[0];
  const float* W_dkv = (const float*)d_in[2];
  const float* b_dkv = (const float*)d_in[3];
  const float* W_uk  = (const float*)d_in[4];
  const float* b_uk  = (const float*)d_in[5];
  const float* W_uv  = (const float*)d_in[6];
  const float* b_uv  = (const float*)d_in[7];
  const float* W_dq  = (const float*)d_in[8];
  const float* b_dq  = (const float*)d_in[9];
  const float* W_uq  = (const float*)d_in[10];
  const float* b_uq  = (const float*)d_in[11];
  const float* W_o   = (const float*)d_in[12];
  const float* b_o   = (const float*)d_in[13];
  float* out = (float*)d_out;

  char* ws = (char*)d_ws;
  size_t off = 0;
  auto carve = [&](size_t bytes) { void* p = ws + off; off += (bytes + 255) & ~(size_t)255; return p; };
  u16* xb     = (u16*)carve((size_t)BS_ * 2048 * 2);      // reused as VT after GEMM1
  u16* WdkvqT = (u16*)carve((size_t)2048 * 2048 * 2);
  u16* WukvT  = (u16*)carve((size_t)4096 * 512 * 2);
  u16* WuqT   = (u16*)carve((size_t)2048 * 1536 * 2);
  u16* WoT    = (u16*)carve((size_t)2048 * 2048 * 2);
  u16* kvq1   = (u16*)carve((size_t)BS_ * 2048 * 2);
  u16* kbuf   = (u16*)carve((size_t)BS_ * 2048 * 2);
  u16* qb     = (u16*)carve((size_t)BS_ * 2048 * 2);
  u16* aob    = (u16*)carve((size_t)BS_ * 2048 * 2);
  float* cs   = (float*)carve((size_t)2048 * 64 * 2 * 4);
  float* bc1  = (float*)carve((size_t)2048 * 4);
  float* bc2  = (float*)carve((size_t)4096 * 4);
  u16* VT     = xb;   // xb dead after GEMM1; V^T [32][128][2048]

  prep<<<dim3(12056), 256, 0, stream>>>(x, xb, W_dkv, W_dq, W_uk, W_uv, W_uq, W_o,
                                        WdkvqT, WukvT, WuqT, WoT,
                                        b_dkv, b_dq, b_uk, b_uv, cs, bc1, bc2);

  // GEMM1: x @ {W_dkv|W_dq} -> kvq1
  gemm_bt<0><<<dim3(2048 / 128, BS_ / 128), 256, 0, stream>>>(xb, 2048, WdkvqT, bc1, kvq1, BS_, 2048, 2048);

  // GEMM2+GEMM3 merged: k (roped) -> kbuf, V^T -> VT, q (roped) -> qb
  gemm23<<<dim3(1536), 256, 0, stream>>>(kvq1, WukvT, WuqT, bc2, b_uq, cs, kbuf, VT, qb);

  attn_kernel<<<dim3(512), 256, 0, stream>>>(qb, kbuf, 2048, VT, aob);

  // GEMM4: attn_out @ W_o -> out (fp32)
  gemm_bt<1><<<dim3(2048 / 128, BS_ / 128), 256, 0, stream>>>(aob, 2048, WoT, b_o, out, BS_, 2048, 2048);
}